// Round 4
// baseline (2090.687 us; speedup 1.0000x reference)
//
#include <hip/hip_runtime.h>
#include <hip/hip_fp16.h>

#define N_NODES 100000
#define N_EDGES 3200000
#define IN_C 256
#define HID 32
#define OUT_C 64
#define NP 100032
#define BINW 64       // nodes per bin
#define BSH 6         // bin = col >> BSH
#define NBIN 1563     // ceil(N_NODES / BINW)
#define NBINP 2048    // padded bin count (pow2 for scans)
#define BCHUNK 4096   // edges per block in hist/scatter

typedef _Float16 f16x8 __attribute__((ext_vector_type(8)));
typedef float f32x4 __attribute__((ext_vector_type(4)));

__device__ __forceinline__ float dot4(const float4 a, const float4 b) {
    return a.x * b.x + a.y * b.y + a.z * b.z + a.w * b.w;
}

// fp16x4 <-> fp32x4 pack helpers
__device__ __forceinline__ float4 h4tof4(uint2 v) {
    __half2 a = *reinterpret_cast<__half2*>(&v.x);
    __half2 b = *reinterpret_cast<__half2*>(&v.y);
    float2 fa = __half22float2(a), fb = __half22float2(b);
    return make_float4(fa.x, fa.y, fb.x, fb.y);
}
__device__ __forceinline__ uint2 f4toh4(float4 f) {
    __half2 a = __float22half2_rn(make_float2(f.x, f.y));
    __half2 b = __float22half2_rn(make_float2(f.z, f.w));
    uint2 v;
    v.x = *reinterpret_cast<unsigned int*>(&a);
    v.y = *reinterpret_cast<unsigned int*>(&b);
    return v;
}

__device__ __forceinline__ unsigned packh2(_Float16 a, _Float16 b) {
    unsigned short ua = __builtin_bit_cast(unsigned short, a);
    unsigned short ub = __builtin_bit_cast(unsigned short, b);
    return (unsigned)ua | ((unsigned)ub << 16);
}

// ---------------- graph build: binned edge reorder ----------------

// A: per-bin edge counts
__global__ __launch_bounds__(256) void k_binhist(const int* __restrict__ col,
                                                 int* __restrict__ binCnt) {
    __shared__ int h[NBIN];
    const int t = threadIdx.x;
    for (int i = t; i < NBIN; i += 256) h[i] = 0;
    __syncthreads();
    const int e0 = blockIdx.x * BCHUNK;
    const int e1 = min(N_EDGES, e0 + BCHUNK);
    for (int i = e0 + t; i < e1; i += 256)
        atomicAdd(&h[col[i] >> BSH], 1);
    __syncthreads();
    for (int i = t; i < NBIN; i += 256)
        if (h[i]) atomicAdd(&binCnt[i], h[i]);
}

// B: exclusive scan of bin counts (NBINP = 2048, one block of 1024, 2/thread)
__global__ __launch_bounds__(1024) void k_binscan(const int* __restrict__ binCnt,
                                                  int* __restrict__ binStart,
                                                  int* __restrict__ binCursor) {
    __shared__ int buf[2][1024];
    const int t = threadIdx.x;
    const int v0 = binCnt[2 * t], v1 = binCnt[2 * t + 1];
    buf[0][t] = v0 + v1;
    __syncthreads();
    int s = 0;
    for (int off = 1; off < 1024; off <<= 1) {
        int d = s ^ 1;
        int val = buf[s][t];
        if (t >= off) val += buf[s][t - off];
        buf[d][t] = val;
        __syncthreads();
        s = d;
    }
    const int excl = buf[s][t] - (v0 + v1);
    binStart[2 * t] = excl;
    binCursor[2 * t] = excl;
    binStart[2 * t + 1] = excl + v0;
    binCursor[2 * t + 1] = excl + v0;
}

// C: LDS-staged scatter of packed edges into bin-contiguous order.
// Pack: p = (row << 6) | (col & 63)   (row < 2^17 -> 23 bits total).
__global__ __launch_bounds__(256) void k_binscatter(const int* __restrict__ row,
                                                    const int* __restrict__ col,
                                                    int* __restrict__ binCursor,
                                                    unsigned* __restrict__ pairs) {
    __shared__ int lcnt[NBINP];
    __shared__ int lofs[NBINP];
    __shared__ int gbase[NBINP];
    __shared__ int sbuf[2][256];
    __shared__ unsigned stage[BCHUNK];
    __shared__ unsigned short sbin[BCHUNK];
    const int t = threadIdx.x;
    for (int i = t; i < NBINP; i += 256) lcnt[i] = 0;
    __syncthreads();

    const int e0 = blockIdx.x * BCHUNK;
    const int e1 = min(N_EDGES, e0 + BCHUNK);
    const int cn = e1 - e0;

    for (int i = e0 + t; i < e1; i += 256)
        atomicAdd(&lcnt[col[i] >> BSH], 1);
    __syncthreads();

    // exclusive scan over 2048 bins: thread t owns bins 8t..8t+7
    int loc[8];
    int run = 0;
    #pragma unroll
    for (int k = 0; k < 8; ++k) { loc[k] = run; run += lcnt[8 * t + k]; }
    sbuf[0][t] = run;
    __syncthreads();
    int s = 0;
    for (int off = 1; off < 256; off <<= 1) {
        int d = s ^ 1;
        int v = sbuf[s][t];
        if (t >= off) v += sbuf[s][t - off];
        sbuf[d][t] = v;
        __syncthreads();
        s = d;
    }
    const int base = sbuf[s][t] - run;
    #pragma unroll
    for (int k = 0; k < 8; ++k) lofs[8 * t + k] = base + loc[k];
    __syncthreads();

    for (int i = t; i < NBINP; i += 256) {
        int c = lcnt[i];
        gbase[i] = c ? atomicAdd(&binCursor[i], c) : 0;
        lcnt[i] = 0;
    }
    __syncthreads();

    for (int i = e0 + t; i < e1; i += 256) {
        int cc = col[i];
        int b = cc >> BSH;
        int p = lofs[b] + atomicAdd(&lcnt[b], 1);
        stage[p] = ((unsigned)row[i] << 6) | (unsigned)(cc & 63);
        sbin[p] = (unsigned short)b;
    }
    __syncthreads();

    for (int i = t; i < cn; i += 256) {
        int b = sbin[i];
        pairs[gbase[b] + (i - lofs[b])] = stage[i];
    }
}

// D: per-node degree + dinv from bin-sorted pairs
__global__ __launch_bounds__(256) void k_bindeg(const unsigned* __restrict__ pairs,
                                                const int* __restrict__ binStart,
                                                const int* __restrict__ binCnt,
                                                int* __restrict__ degc,
                                                float* __restrict__ dinv) {
    __shared__ int cur[BINW];
    const int t = threadIdx.x;
    if (t < BINW) cur[t] = 0;
    __syncthreads();
    const int bin = blockIdx.x;
    const int s = binStart[bin], cn = binCnt[bin];
    for (int i = t; i < cn; i += 256)
        atomicAdd(&cur[pairs[s + i] & 63u], 1);
    __syncthreads();
    if (t < BINW) {
        int n = bin * BINW + t;
        if (n < N_NODES) {
            degc[n] = cur[t];
            dinv[n] = 1.0f / sqrtf((float)(cur[t] + 1));  // +1 self loop
        }
    }
}

// ---------------- graph build: fallback path (two-pass compact CSR) ----------

__global__ void k_hist(const int* __restrict__ col, int* __restrict__ deg) {
    int i = blockIdx.x * 256 + threadIdx.x;
    if (i < N_EDGES) atomicAdd(&deg[col[i]], 1);
}

__global__ void k_scan1(const int* __restrict__ deg, int* __restrict__ rowptr,
                        int* __restrict__ bsum) {
    __shared__ int buf[2][1024];
    const int t = threadIdx.x, b = blockIdx.x;
    const int i = b * 1024 + t;
    int v = (i < N_NODES) ? deg[i] : 0;
    buf[0][t] = v;
    __syncthreads();
    int src = 0;
    for (int off = 1; off < 1024; off <<= 1) {
        int dst = src ^ 1;
        int val = buf[src][t];
        if (t >= off) val += buf[src][t - off];
        buf[dst][t] = val;
        __syncthreads();
        src = dst;
    }
    int incl = buf[src][t];
    if (i < N_NODES) rowptr[i] = incl - v;
    if (t == 1023) bsum[b] = incl;
}

__global__ void k_scan2(int* __restrict__ bsum, int nb) {
    __shared__ int buf[2][128];
    const int t = threadIdx.x;
    int v = (t < nb) ? bsum[t] : 0;
    buf[0][t] = v;
    __syncthreads();
    int src = 0;
    for (int off = 1; off < 128; off <<= 1) {
        int dst = src ^ 1;
        int val = buf[src][t];
        if (t >= off) val += buf[src][t - off];
        buf[dst][t] = val;
        __syncthreads();
        src = dst;
    }
    if (t < nb) bsum[t] = buf[src][t] - v;
}

__global__ void k_scan3(int* __restrict__ rowptr, const int* __restrict__ bsum) {
    int i = blockIdx.x * 256 + threadIdx.x;
    if (i < N_NODES) rowptr[i] += bsum[i >> 10];
}

__global__ void k_dinv(const int* __restrict__ cnt, int stride,
                       float* __restrict__ dinv, int* __restrict__ degc) {
    int i = blockIdx.x * 256 + threadIdx.x;
    if (i < N_NODES) {
        int d = cnt[i * stride];
        degc[i] = d;
        dinv[i] = 1.0f / sqrtf((float)(d + 1));
    }
}

__global__ void k_scatter(const int* __restrict__ row, const int* __restrict__ col,
                          const int* __restrict__ rowptr, int* __restrict__ cursor,
                          int* __restrict__ csr) {
    int i = blockIdx.x * 256 + threadIdx.x;
    if (i < N_EDGES) {
        int c = col[i];
        int pos = rowptr[c] + atomicAdd(&cursor[c], 1);
        csr[pos] = row[i];
    }
}

// ---------------- dense layer 0 (MFMA), plane-split store ----------------
// gLo/gHi: plane pointers; ns = node stride in uint2 units (4 = split planes,
// 8 with gHi = gLo+4 = legacy interleaved for fallback).
__global__ __launch_bounds__(256) void k_lin0_mfma(
        const float* __restrict__ x,
        const float* __restrict__ W0,   // [32][256]
        const float* __restrict__ b0,   // [32]
        const float* __restrict__ dinv,
        uint2* __restrict__ gLo, uint2* __restrict__ gHi, int ns) {
    __shared__ f16x8 WH[1024];   // [mt(2)][ks(8)][lane(64)] fragment-packed
    __shared__ f16x8 WL[1024];

    const int t = threadIdx.x;
    const int w = t >> 6;        // wave 0..3
    const int l = t & 63;
    const int lr = l & 15;       // within-tile row/col index
    const int lg = l >> 4;       // k-group 0..3

    for (int s = t; s < 1024; s += 256) {
        const int lane = s & 63;
        const int mtks = s >> 6;
        const int ks = mtks & 7, mt = mtks >> 3;
        const float* wr = W0 + (size_t)(mt * 16 + (lane & 15)) * IN_C
                             + ks * 32 + (lane >> 4) * 8;
        float4 a0 = *(const float4*)(wr);
        float4 a1 = *(const float4*)(wr + 4);
        float v[8] = {a0.x, a0.y, a0.z, a0.w, a1.x, a1.y, a1.z, a1.w};
        f16x8 h, lo;
        #pragma unroll
        for (int e = 0; e < 8; ++e) {
            float sv = v[e] * 16.0f;          // prescale: Wl stays f16-normal
            _Float16 hh = (_Float16)sv;
            h[e] = hh;
            lo[e] = (_Float16)(sv - (float)hh);
        }
        WH[s] = h;
        WL[s] = lo;
    }
    __syncthreads();

    const int unit = blockIdx.x * 4 + w;       // 32 nodes per unit
    if (unit * 32 >= N_NODES) return;
    const int n0 = unit * 32;

    f32x4 acc[2][2];
    #pragma unroll
    for (int mt = 0; mt < 2; ++mt)
        #pragma unroll
        for (int nt = 0; nt < 2; ++nt)
            acc[mt][nt] = (f32x4){0.f, 0.f, 0.f, 0.f};

    const float* xr0 = x + (size_t)(n0 + lr) * IN_C + lg * 8;        // nt=0
    const float* xr1 = x + (size_t)(n0 + 16 + lr) * IN_C + lg * 8;   // nt=1

    #pragma unroll
    for (int ks = 0; ks < 8; ++ks) {
        float4 u0 = *(const float4*)(xr0 + ks * 32);
        float4 u1 = *(const float4*)(xr0 + ks * 32 + 4);
        float4 v0 = *(const float4*)(xr1 + ks * 32);
        float4 v1 = *(const float4*)(xr1 + ks * 32 + 4);
        float fu[8] = {u0.x, u0.y, u0.z, u0.w, u1.x, u1.y, u1.z, u1.w};
        float fv[8] = {v0.x, v0.y, v0.z, v0.w, v1.x, v1.y, v1.z, v1.w};
        f16x8 xh0, xl0, xh1, xl1;
        #pragma unroll
        for (int e = 0; e < 8; ++e) {
            _Float16 h0 = (_Float16)fu[e];
            xh0[e] = h0;
            xl0[e] = (_Float16)(fu[e] - (float)h0);
            _Float16 h1 = (_Float16)fv[e];
            xh1[e] = h1;
            xl1[e] = (_Float16)(fv[e] - (float)h1);
        }
        #pragma unroll
        for (int mt = 0; mt < 2; ++mt) {
            f16x8 wh = WH[mt * 512 + ks * 64 + l];
            f16x8 wl = WL[mt * 512 + ks * 64 + l];
            acc[mt][0] = __builtin_amdgcn_mfma_f32_16x16x32_f16(wh, xh0, acc[mt][0], 0, 0, 0);
            acc[mt][0] = __builtin_amdgcn_mfma_f32_16x16x32_f16(wh, xl0, acc[mt][0], 0, 0, 0);
            acc[mt][0] = __builtin_amdgcn_mfma_f32_16x16x32_f16(wl, xh0, acc[mt][0], 0, 0, 0);
            acc[mt][1] = __builtin_amdgcn_mfma_f32_16x16x32_f16(wh, xh1, acc[mt][1], 0, 0, 0);
            acc[mt][1] = __builtin_amdgcn_mfma_f32_16x16x32_f16(wh, xl1, acc[mt][1], 0, 0, 0);
            acc[mt][1] = __builtin_amdgcn_mfma_f32_16x16x32_f16(wl, xh1, acc[mt][1], 0, 0, 0);
        }
    }

    #pragma unroll
    for (int nt = 0; nt < 2; ++nt) {
        const int node = n0 + nt * 16 + lr;
        const float dv = dinv[node];
        #pragma unroll
        for (int mt = 0; mt < 2; ++mt) {
            const float4 bb = *(const float4*)(b0 + mt * 16 + lg * 4);
            f32x4 a = acc[mt][nt];
            float4 r = make_float4((a[0] * 0.0625f + bb.x) * dv,
                                   (a[1] * 0.0625f + bb.y) * dv,
                                   (a[2] * 0.0625f + bb.z) * dv,
                                   (a[3] * 0.0625f + bb.w) * dv);
            uint2* dst = mt ? gHi : gLo;
            dst[(size_t)node * ns + lg] = f4toh4(r);
        }
    }
}

// ---------------- push-style propagate (fast path) ----------------
// plane: [node][part(2)] uint4 = 16 fp16 channels per node (3.2 MB -> L2-resident).
// Per bin (64 nodes): edge-parallel LDS accumulate, acc transposed [ch][node]
// so ds_add_f32 banks are spread by the random target index.

// pass 1: lo plane -> agg (f32 [node][16])
__global__ __launch_bounds__(256) void k_push_acc(
        const uint4* __restrict__ plane, const unsigned* __restrict__ pairs,
        const int* __restrict__ binStart, const int* __restrict__ binCnt,
        float* __restrict__ agg) {
    __shared__ float acc[16][BINW];
    const int t = threadIdx.x;
    const int bin = blockIdx.x, base = bin * BINW;

    if (t < 128) {                      // self-loop init
        int nl = t >> 1, part = t & 1;
        int n = base + nl;
        float v[8] = {0.f, 0.f, 0.f, 0.f, 0.f, 0.f, 0.f, 0.f};
        if (n < N_NODES) {
            uint4 u = plane[(size_t)n * 2 + part];
            __half2* hp = (__half2*)&u;
            #pragma unroll
            for (int i = 0; i < 4; ++i) {
                float2 f = __half22float2(hp[i]);
                v[2 * i] = f.x; v[2 * i + 1] = f.y;
            }
        }
        #pragma unroll
        for (int k = 0; k < 8; ++k) acc[part * 8 + k][nl] = v[k];
    }
    __syncthreads();

    const int s = binStart[bin], cn = binCnt[bin];
    for (int w = t; w < cn * 2; w += 256) {
        unsigned p = pairs[s + (w >> 1)];
        const int part = w & 1;
        const int c = (int)(p & 63u);
        const int r = (int)(p >> 6);
        uint4 u = plane[(size_t)r * 2 + part];
        __half2* hp = (__half2*)&u;
        #pragma unroll
        for (int i = 0; i < 4; ++i) {
            float2 f = __half22float2(hp[i]);
            atomicAdd(&acc[part * 8 + 2 * i][c], f.x);
            atomicAdd(&acc[part * 8 + 2 * i + 1][c], f.y);
        }
    }
    __syncthreads();

    {
        int nl = t >> 2;
        int n = base + nl;
        if (n < N_NODES) {
            int q = (t & 3) * 4;
            float4 v = make_float4(acc[q][nl], acc[q + 1][nl],
                                   acc[q + 2][nl], acc[q + 3][nl]);
            *(float4*)&agg[(size_t)n * 16 + q] = v;
        }
    }
}

// pass 2: hi plane gather + dense agg read + W(32x32) MFMA + plane-split store
__global__ __launch_bounds__(256) void k_push_prop(
        const uint4* __restrict__ planeHi, const unsigned* __restrict__ pairs,
        const int* __restrict__ binStart, const int* __restrict__ binCnt,
        const float* __restrict__ agg, const float* __restrict__ dinv,
        const float* __restrict__ W, const float* __restrict__ b,
        uint2* __restrict__ outLo, uint2* __restrict__ outHi) {
    __shared__ float acc[16][BINW];
    __shared__ f16x8 WH[128], WL[128];
    const int t = threadIdx.x;
    const int bin = blockIdx.x, base = bin * BINW;

    if (t < 128) {
        const int lane = t & 63, mt = t >> 6;
        const float* wr = W + (size_t)(mt * 16 + (lane & 15)) * HID + (lane >> 4) * 8;
        f16x8 h, lo;
        #pragma unroll
        for (int e = 0; e < 8; ++e) {
            float sv = wr[e] * 8.0f;
            _Float16 hh = (_Float16)sv;
            h[e] = hh;
            lo[e] = (_Float16)(sv - (float)hh);
        }
        WH[t] = h;
        WL[t] = lo;
    }
    if (t < 128) {                      // self-loop init (hi plane)
        int nl = t >> 1, part = t & 1;
        int n = base + nl;
        float v[8] = {0.f, 0.f, 0.f, 0.f, 0.f, 0.f, 0.f, 0.f};
        if (n < N_NODES) {
            uint4 u = planeHi[(size_t)n * 2 + part];
            __half2* hp = (__half2*)&u;
            #pragma unroll
            for (int i = 0; i < 4; ++i) {
                float2 f = __half22float2(hp[i]);
                v[2 * i] = f.x; v[2 * i + 1] = f.y;
            }
        }
        #pragma unroll
        for (int k = 0; k < 8; ++k) acc[part * 8 + k][nl] = v[k];
    }
    __syncthreads();

    const int s = binStart[bin], cn = binCnt[bin];
    for (int w = t; w < cn * 2; w += 256) {
        unsigned p = pairs[s + (w >> 1)];
        const int part = w & 1;
        const int c = (int)(p & 63u);
        const int r = (int)(p >> 6);
        uint4 u = planeHi[(size_t)r * 2 + part];
        __half2* hp = (__half2*)&u;
        #pragma unroll
        for (int i = 0; i < 4; ++i) {
            float2 f = __half22float2(hp[i]);
            atomicAdd(&acc[part * 8 + 2 * i][c], f.x);
            atomicAdd(&acc[part * 8 + 2 * i + 1][c], f.y);
        }
    }
    __syncthreads();

    // MFMA: wave w handles nodes base + w*16 .. +15
    const int wv = t >> 6, l = t & 63;
    const int nl = (wv << 4) + (l & 15);
    const int node = base + nl;
    const int nsafe = min(node, N_NODES - 1);
    const int lg = l >> 4;

    float av[8];
    if (lg < 2) {
        const float* ap = agg + (size_t)nsafe * 16 + lg * 8;
        float4 u0 = *(const float4*)ap;
        float4 u1 = *(const float4*)(ap + 4);
        av[0] = u0.x; av[1] = u0.y; av[2] = u0.z; av[3] = u0.w;
        av[4] = u1.x; av[5] = u1.y; av[6] = u1.z; av[7] = u1.w;
    } else {
        #pragma unroll
        for (int k = 0; k < 8; ++k) av[k] = acc[(lg - 2) * 8 + k][nl];
    }

    f16x8 bh, bl;
    #pragma unroll
    for (int i = 0; i < 8; ++i) {
        _Float16 hh = (_Float16)av[i];
        bh[i] = hh;
        bl[i] = (_Float16)(av[i] - (float)hh);
    }

    f32x4 c0 = (f32x4){0.f, 0.f, 0.f, 0.f};
    f32x4 c1 = (f32x4){0.f, 0.f, 0.f, 0.f};
    {
        f16x8 wh0 = WH[l], wl0 = WL[l];
        f16x8 wh1 = WH[64 + l], wl1 = WL[64 + l];
        c0 = __builtin_amdgcn_mfma_f32_16x16x32_f16(wh0, bh, c0, 0, 0, 0);
        c0 = __builtin_amdgcn_mfma_f32_16x16x32_f16(wh0, bl, c0, 0, 0, 0);
        c0 = __builtin_amdgcn_mfma_f32_16x16x32_f16(wl0, bh, c0, 0, 0, 0);
        c1 = __builtin_amdgcn_mfma_f32_16x16x32_f16(wh1, bh, c1, 0, 0, 0);
        c1 = __builtin_amdgcn_mfma_f32_16x16x32_f16(wh1, bl, c1, 0, 0, 0);
        c1 = __builtin_amdgcn_mfma_f32_16x16x32_f16(wl1, bh, c1, 0, 0, 0);
    }

    if (node < N_NODES) {
        const float dv = dinv[node];
        #pragma unroll
        for (int mt = 0; mt < 2; ++mt) {
            const f32x4 bb = *(const f32x4*)(b + mt * 16 + lg * 4);
            f32x4 a = mt ? c1 : c0;
            float4 r;
            r.x = fmaxf(bb[0] + dv * (a[0] * 0.125f), 0.f) * dv;
            r.y = fmaxf(bb[1] + dv * (a[1] * 0.125f), 0.f) * dv;
            r.z = fmaxf(bb[2] + dv * (a[2] * 0.125f), 0.f) * dv;
            r.w = fmaxf(bb[3] + dv * (a[3] * 0.125f), 0.f) * dv;
            uint2* dst = mt ? outHi : outLo;
            dst[(size_t)node * 4 + lg] = f4toh4(r);
        }
    }
}

// pass 2 (last layer): hi gather + agg -> W3,relu -> shuffle -> W4 -> out
__global__ __launch_bounds__(256) void k_push_last(
        const uint4* __restrict__ planeHi, const unsigned* __restrict__ pairs,
        const int* __restrict__ binStart, const int* __restrict__ binCnt,
        const float* __restrict__ agg, const float* __restrict__ dinv,
        const float* __restrict__ W3, const float* __restrict__ b3,
        const float* __restrict__ W4, const float* __restrict__ b4,
        float4* __restrict__ out4) {
    __shared__ float acc[16][BINW];
    __shared__ f16x8 WH3[128], WL3[128];
    __shared__ f16x8 WH4[256], WL4[256];
    const int t = threadIdx.x;
    const int bin = blockIdx.x, base = bin * BINW;

    if (t < 128) {
        const int lane = t & 63, mt = t >> 6;
        const float* wr = W3 + (size_t)(mt * 16 + (lane & 15)) * HID + (lane >> 4) * 8;
        f16x8 h, lo;
        #pragma unroll
        for (int e = 0; e < 8; ++e) {
            float sv = wr[e] * 8.0f;
            _Float16 hh = (_Float16)sv;
            h[e] = hh;
            lo[e] = (_Float16)(sv - (float)hh);
        }
        WH3[t] = h;
        WL3[t] = lo;
    }
    {
        const int lane = t & 63, mt = t >> 6;   // mt 0..3
        const float* wr = W4 + (size_t)(mt * 16 + (lane & 15)) * HID + (lane >> 4) * 8;
        f16x8 h, lo;
        #pragma unroll
        for (int e = 0; e < 8; ++e) {
            float sv = wr[e] * 8.0f;
            _Float16 hh = (_Float16)sv;
            h[e] = hh;
            lo[e] = (_Float16)(sv - (float)hh);
        }
        WH4[t] = h;
        WL4[t] = lo;
    }
    if (t < 128) {                      // self-loop init (hi plane)
        int nl_ = t >> 1, part = t & 1;
        int n = base + nl_;
        float v[8] = {0.f, 0.f, 0.f, 0.f, 0.f, 0.f, 0.f, 0.f};
        if (n < N_NODES) {
            uint4 u = planeHi[(size_t)n * 2 + part];
            __half2* hp = (__half2*)&u;
            #pragma unroll
            for (int i = 0; i < 4; ++i) {
                float2 f = __half22float2(hp[i]);
                v[2 * i] = f.x; v[2 * i + 1] = f.y;
            }
        }
        #pragma unroll
        for (int k = 0; k < 8; ++k) acc[part * 8 + k][nl_] = v[k];
    }
    __syncthreads();

    const int s = binStart[bin], cn = binCnt[bin];
    for (int w = t; w < cn * 2; w += 256) {
        unsigned p = pairs[s + (w >> 1)];
        const int part = w & 1;
        const int c = (int)(p & 63u);
        const int r = (int)(p >> 6);
        uint4 u = planeHi[(size_t)r * 2 + part];
        __half2* hp = (__half2*)&u;
        #pragma unroll
        for (int i = 0; i < 4; ++i) {
            float2 f = __half22float2(hp[i]);
            atomicAdd(&acc[part * 8 + 2 * i][c], f.x);
            atomicAdd(&acc[part * 8 + 2 * i + 1][c], f.y);
        }
    }
    __syncthreads();

    const int wv = t >> 6, l = t & 63;
    const int nl = l & 15;
    const int nloc = (wv << 4) + nl;
    const int node = base + nloc;
    const int nsafe = min(node, N_NODES - 1);
    const int lg = l >> 4;

    float av[8];
    if (lg < 2) {
        const float* ap = agg + (size_t)nsafe * 16 + lg * 8;
        float4 u0 = *(const float4*)ap;
        float4 u1 = *(const float4*)(ap + 4);
        av[0] = u0.x; av[1] = u0.y; av[2] = u0.z; av[3] = u0.w;
        av[4] = u1.x; av[5] = u1.y; av[6] = u1.z; av[7] = u1.w;
    } else {
        #pragma unroll
        for (int k = 0; k < 8; ++k) av[k] = acc[(lg - 2) * 8 + k][nloc];
    }

    f16x8 bh, bl;
    #pragma unroll
    for (int i = 0; i < 8; ++i) {
        _Float16 hh = (_Float16)av[i];
        bh[i] = hh;
        bl[i] = (_Float16)(av[i] - (float)hh);
    }

    // stage 1: y = W3 @ agg, h = relu(b3 + dv*y)
    f32x4 c0 = (f32x4){0.f, 0.f, 0.f, 0.f};
    f32x4 c1 = (f32x4){0.f, 0.f, 0.f, 0.f};
    {
        f16x8 wh0 = WH3[l], wl0 = WL3[l];
        f16x8 wh1 = WH3[64 + l], wl1 = WL3[64 + l];
        c0 = __builtin_amdgcn_mfma_f32_16x16x32_f16(wh0, bh, c0, 0, 0, 0);
        c0 = __builtin_amdgcn_mfma_f32_16x16x32_f16(wh0, bl, c0, 0, 0, 0);
        c0 = __builtin_amdgcn_mfma_f32_16x16x32_f16(wl0, bh, c0, 0, 0, 0);
        c1 = __builtin_amdgcn_mfma_f32_16x16x32_f16(wh1, bh, c1, 0, 0, 0);
        c1 = __builtin_amdgcn_mfma_f32_16x16x32_f16(wh1, bl, c1, 0, 0, 0);
        c1 = __builtin_amdgcn_mfma_f32_16x16x32_f16(wl1, bh, c1, 0, 0, 0);
    }

    const float dv = dinv[nsafe];
    const f32x4 b3a = *(const f32x4*)(b3 + lg * 4);
    const f32x4 b3b = *(const f32x4*)(b3 + 16 + lg * 4);
    float h0[4], h1[4];
    #pragma unroll
    for (int r = 0; r < 4; ++r) {
        h0[r] = fmaxf(b3a[r] + dv * (c0[r] * 0.125f), 0.f);
        h1[r] = fmaxf(b3b[r] + dv * (c1[r] * 0.125f), 0.f);
    }

    // f16-split h, packed as half2 words
    unsigned ph[2][2], pl_[2][2];
    #pragma unroll
    for (int p = 0; p < 2; ++p) {
        _Float16 a0 = (_Float16)h0[2 * p], a1 = (_Float16)h0[2 * p + 1];
        _Float16 l0 = (_Float16)(h0[2 * p] - (float)a0);
        _Float16 l1 = (_Float16)(h0[2 * p + 1] - (float)a1);
        ph[0][p] = packh2(a0, a1);
        pl_[0][p] = packh2(l0, l1);
        _Float16 c0_ = (_Float16)h1[2 * p], c1_ = (_Float16)h1[2 * p + 1];
        _Float16 d0 = (_Float16)(h1[2 * p] - (float)c0_);
        _Float16 d1 = (_Float16)(h1[2 * p + 1] - (float)c1_);
        ph[1][p] = packh2(c0_, c1_);
        pl_[1][p] = packh2(d0, d1);
    }

    // redistribute: dest lane (nl,lg) needs h-ch lg*8..+7 of node nl (within wave)
    union { unsigned u[4]; f16x8 v; } Bh, Bl;
    #pragma unroll
    for (int q = 0; q < 4; ++q) {
        int src = nl + 16 * ((lg & 1) * 2 + (q >> 1));
        unsigned a0 = (unsigned)__shfl((int)ph[0][q & 1], src, 64);
        unsigned a1 = (unsigned)__shfl((int)ph[1][q & 1], src, 64);
        Bh.u[q] = (lg >= 2) ? a1 : a0;
        unsigned c0_ = (unsigned)__shfl((int)pl_[0][q & 1], src, 64);
        unsigned c1_ = (unsigned)__shfl((int)pl_[1][q & 1], src, 64);
        Bl.u[q] = (lg >= 2) ? c1_ : c0_;
    }

    // stage 2: out = W4 @ h + b4 (4 out-ch tiles)
    f32x4 o0 = (f32x4){0.f, 0.f, 0.f, 0.f};
    f32x4 o1 = (f32x4){0.f, 0.f, 0.f, 0.f};
    f32x4 o2 = (f32x4){0.f, 0.f, 0.f, 0.f};
    f32x4 o3 = (f32x4){0.f, 0.f, 0.f, 0.f};
    {
        f16x8 wh, wl;
        wh = WH4[l];        wl = WL4[l];
        o0 = __builtin_amdgcn_mfma_f32_16x16x32_f16(wh, Bh.v, o0, 0, 0, 0);
        o0 = __builtin_amdgcn_mfma_f32_16x16x32_f16(wh, Bl.v, o0, 0, 0, 0);
        o0 = __builtin_amdgcn_mfma_f32_16x16x32_f16(wl, Bh.v, o0, 0, 0, 0);
        wh = WH4[64 + l];   wl = WL4[64 + l];
        o1 = __builtin_amdgcn_mfma_f32_16x16x32_f16(wh, Bh.v, o1, 0, 0, 0);
        o1 = __builtin_amdgcn_mfma_f32_16x16x32_f16(wh, Bl.v, o1, 0, 0, 0);
        o1 = __builtin_amdgcn_mfma_f32_16x16x32_f16(wl, Bh.v, o1, 0, 0, 0);
        wh = WH4[128 + l];  wl = WL4[128 + l];
        o2 = __builtin_amdgcn_mfma_f32_16x16x32_f16(wh, Bh.v, o2, 0, 0, 0);
        o2 = __builtin_amdgcn_mfma_f32_16x16x32_f16(wh, Bl.v, o2, 0, 0, 0);
        o2 = __builtin_amdgcn_mfma_f32_16x16x32_f16(wl, Bh.v, o2, 0, 0, 0);
        wh = WH4[192 + l];  wl = WL4[192 + l];
        o3 = __builtin_amdgcn_mfma_f32_16x16x32_f16(wh, Bh.v, o3, 0, 0, 0);
        o3 = __builtin_amdgcn_mfma_f32_16x16x32_f16(wh, Bl.v, o3, 0, 0, 0);
        o3 = __builtin_amdgcn_mfma_f32_16x16x32_f16(wl, Bh.v, o3, 0, 0, 0);
    }

    if (node < N_NODES) {
        #pragma unroll
        for (int mt = 0; mt < 4; ++mt) {
            const f32x4 bb = *(const f32x4*)(b4 + mt * 16 + lg * 4);
            f32x4 a = (mt == 0) ? o0 : (mt == 1) ? o1 : (mt == 2) ? o2 : o3;
            out4[(size_t)node * 16 + mt * 4 + lg] =
                make_float4(a[0] * 0.125f + bb[0], a[1] * 0.125f + bb[1],
                            a[2] * 0.125f + bb[2], a[3] * 0.125f + bb[3]);
        }
    }
}

// ---------------- legacy fused propagate + linear (fallback path) ----------

__global__ __launch_bounds__(256) void k_prop2(
        const uint2* __restrict__ g2, const int* __restrict__ idx,
        const int* __restrict__ base_arr,
        const int* __restrict__ cnt_arr, int maxcnt,
        const float* __restrict__ dinv,
        const float* __restrict__ W, const float* __restrict__ b,
        uint2* __restrict__ gout2) {
    __shared__ float4 Ws[HID * 9];
    const int t = threadIdx.x;
    { int c = t >> 3, k4 = t & 7; Ws[c * 9 + k4] = ((const float4*)W)[t]; }
    __syncthreads();

    const int l = t & 7;
    const int n = blockIdx.x * 32 + (t >> 3);
    if (n >= N_NODES) return;

    int cnt = cnt_arr[n];
    if (cnt > maxcnt) cnt = maxcnt;
    const int base = base_arr[n];
    const int* __restrict__ e = idx + base;

    float4 acc = h4tof4(g2[n * 8 + l]);
    int j = 0;
    for (; j + 8 <= cnt; j += 8) {
        int r0 = e[j], r1 = e[j + 1], r2 = e[j + 2], r3 = e[j + 3];
        int r4 = e[j + 4], r5 = e[j + 5], r6 = e[j + 6], r7 = e[j + 7];
        uint2 v0 = g2[r0 * 8 + l], v1 = g2[r1 * 8 + l];
        uint2 v2 = g2[r2 * 8 + l], v3 = g2[r3 * 8 + l];
        uint2 v4 = g2[r4 * 8 + l], v5 = g2[r5 * 8 + l];
        uint2 v6 = g2[r6 * 8 + l], v7 = g2[r7 * 8 + l];
        float4 a0 = h4tof4(v0), a1 = h4tof4(v1), a2 = h4tof4(v2), a3 = h4tof4(v3);
        float4 a4 = h4tof4(v4), a5 = h4tof4(v5), a6 = h4tof4(v6), a7 = h4tof4(v7);
        acc.x += a0.x + a1.x + a2.x + a3.x + a4.x + a5.x + a6.x + a7.x;
        acc.y += a0.y + a1.y + a2.y + a3.y + a4.y + a5.y + a6.y + a7.y;
        acc.z += a0.z + a1.z + a2.z + a3.z + a4.z + a5.z + a6.z + a7.z;
        acc.w += a0.w + a1.w + a2.w + a3.w + a4.w + a5.w + a6.w + a7.w;
    }
    for (; j < cnt; ++j) {
        float4 a = h4tof4(g2[e[j] * 8 + l]);
        acc.x += a.x; acc.y += a.y; acc.z += a.z; acc.w += a.w;
    }

    const float dv = dinv[n];
    float4 y = make_float4(0.f, 0.f, 0.f, 0.f);
    #pragma unroll
    for (int m = 0; m < 8; ++m) {
        float4 sv;
        sv.x = __shfl(acc.x, m, 8);
        sv.y = __shfl(acc.y, m, 8);
        sv.z = __shfl(acc.z, m, 8);
        sv.w = __shfl(acc.w, m, 8);
        y.x += dot4(Ws[(4 * l + 0) * 9 + m], sv);
        y.y += dot4(Ws[(4 * l + 1) * 9 + m], sv);
        y.z += dot4(Ws[(4 * l + 2) * 9 + m], sv);
        y.w += dot4(Ws[(4 * l + 3) * 9 + m], sv);
    }
    const float4 bb = ((const float4*)b)[l];
    y.x = fmaxf(bb.x + dv * y.x, 0.f) * dv;
    y.y = fmaxf(bb.y + dv * y.y, 0.f) * dv;
    y.z = fmaxf(bb.z + dv * y.z, 0.f) * dv;
    y.w = fmaxf(bb.w + dv * y.w, 0.f) * dv;
    gout2[n * 8 + l] = f4toh4(y);
}

__global__ __launch_bounds__(256) void k_last2(
        const uint2* __restrict__ g2, const int* __restrict__ idx,
        const int* __restrict__ base_arr,
        const int* __restrict__ cnt_arr, int maxcnt,
        const float* __restrict__ dinv,
        const float* __restrict__ W3, const float* __restrict__ b3,
        const float* __restrict__ W4, const float* __restrict__ b4,
        float4* __restrict__ out4) {
    __shared__ float4 W3s[HID * 9];
    __shared__ float4 W4s[OUT_C * 9];
    const int t = threadIdx.x;
    { int c = t >> 3, k4 = t & 7; W3s[c * 9 + k4] = ((const float4*)W3)[t]; }
    #pragma unroll
    for (int f = t; f < 512; f += 256) {
        int c = f >> 3, k4 = f & 7;
        W4s[c * 9 + k4] = ((const float4*)W4)[f];
    }
    __syncthreads();

    const int l = t & 7;
    const int n = blockIdx.x * 32 + (t >> 3);
    if (n >= N_NODES) return;

    int cnt = cnt_arr[n];
    if (cnt > maxcnt) cnt = maxcnt;
    const int base = base_arr[n];
    const int* __restrict__ e = idx + base;

    float4 acc = h4tof4(g2[n * 8 + l]);
    int j = 0;
    for (; j + 8 <= cnt; j += 8) {
        int r0 = e[j], r1 = e[j + 1], r2 = e[j + 2], r3 = e[j + 3];
        int r4 = e[j + 4], r5 = e[j + 5], r6 = e[j + 6], r7 = e[j + 7];
        uint2 v0 = g2[r0 * 8 + l], v1 = g2[r1 * 8 + l];
        uint2 v2 = g2[r2 * 8 + l], v3 = g2[r3 * 8 + l];
        uint2 v4 = g2[r4 * 8 + l], v5 = g2[r5 * 8 + l];
        uint2 v6 = g2[r6 * 8 + l], v7 = g2[r7 * 8 + l];
        float4 a0 = h4tof4(v0), a1 = h4tof4(v1), a2 = h4tof4(v2), a3 = h4tof4(v3);
        float4 a4 = h4tof4(v4), a5 = h4tof4(v5), a6 = h4tof4(v6), a7 = h4tof4(v7);
        acc.x += a0.x + a1.x + a2.x + a3.x + a4.x + a5.x + a6.x + a7.x;
        acc.y += a0.y + a1.y + a2.y + a3.y + a4.y + a5.y + a6.y + a7.y;
        acc.z += a0.z + a1.z + a2.z + a3.z + a4.z + a5.z + a6.z + a7.z;
        acc.w += a0.w + a1.w + a2.w + a3.w + a4.w + a5.w + a6.w + a7.w;
    }
    for (; j < cnt; ++j) {
        float4 a = h4tof4(g2[e[j] * 8 + l]);
        acc.x += a.x; acc.y += a.y; acc.z += a.z; acc.w += a.w;
    }

    const float dv = dinv[n];
    float4 y = make_float4(0.f, 0.f, 0.f, 0.f);
    #pragma unroll
    for (int m = 0; m < 8; ++m) {
        float4 sv;
        sv.x = __shfl(acc.x, m, 8);
        sv.y = __shfl(acc.y, m, 8);
        sv.z = __shfl(acc.z, m, 8);
        sv.w = __shfl(acc.w, m, 8);
        y.x += dot4(W3s[(4 * l + 0) * 9 + m], sv);
        y.y += dot4(W3s[(4 * l + 1) * 9 + m], sv);
        y.z += dot4(W3s[(4 * l + 2) * 9 + m], sv);
        y.w += dot4(W3s[(4 * l + 3) * 9 + m], sv);
    }
    const float4 b3v = ((const float4*)b3)[l];
    float4 h;
    h.x = fmaxf(b3v.x + dv * y.x, 0.f);
    h.y = fmaxf(b3v.y + dv * y.y, 0.f);
    h.z = fmaxf(b3v.z + dv * y.z, 0.f);
    h.w = fmaxf(b3v.w + dv * y.w, 0.f);

    float4 ya = make_float4(0.f, 0.f, 0.f, 0.f);
    float4 yb = make_float4(0.f, 0.f, 0.f, 0.f);
    #pragma unroll
    for (int m = 0; m < 8; ++m) {
        float4 hv;
        hv.x = __shfl(h.x, m, 8);
        hv.y = __shfl(h.y, m, 8);
        hv.z = __shfl(h.z, m, 8);
        hv.w = __shfl(h.w, m, 8);
        ya.x += dot4(W4s[(4 * l + 0) * 9 + m], hv);
        ya.y += dot4(W4s[(4 * l + 1) * 9 + m], hv);
        ya.z += dot4(W4s[(4 * l + 2) * 9 + m], hv);
        ya.w += dot4(W4s[(4 * l + 3) * 9 + m], hv);
        yb.x += dot4(W4s[(32 + 4 * l + 0) * 9 + m], hv);
        yb.y += dot4(W4s[(32 + 4 * l + 1) * 9 + m], hv);
        yb.z += dot4(W4s[(32 + 4 * l + 2) * 9 + m], hv);
        yb.w += dot4(W4s[(32 + 4 * l + 3) * 9 + m], hv);
    }
    const float4 b4a = ((const float4*)b4)[l];
    const float4 b4b = ((const float4*)b4)[8 + l];
    ya.x += b4a.x; ya.y += b4a.y; ya.z += b4a.z; ya.w += b4a.w;
    yb.x += b4b.x; yb.y += b4b.y; yb.z += b4b.z; yb.w += b4b.w;
    out4[n * 16 + l] = ya;
    out4[n * 16 + 8 + l] = yb;
}

// ---------------- launcher ----------------

extern "C" void kernel_launch(void* const* d_in, const int* in_sizes, int n_in,
                              void* d_out, int out_size, void* d_ws, size_t ws_size,
                              hipStream_t stream) {
    const float* x   = (const float*)d_in[0];
    const int*   ei  = (const int*)d_in[1];
    const int*   row = ei;             // sources
    const int*   col = ei + N_EDGES;   // targets
    const float* W0 = (const float*)d_in[2];
    const float* b0 = (const float*)d_in[3];
    const float* W1 = (const float*)d_in[4];
    const float* b1 = (const float*)d_in[5];
    const float* W2 = (const float*)d_in[6];
    const float* b2 = (const float*)d_in[7];
    const float* W3 = (const float*)d_in[8];
    const float* b3 = (const float*)d_in[9];
    const float* W4 = (const float*)d_in[10];
    const float* b4 = (const float*)d_in[11];
    float* out = (float*)d_out;

    const int EB = (N_EDGES + 255) / 256;           // 12500
    const int NB256 = (N_NODES + 255) / 256;        // 391
    const int NB1024 = (N_NODES + 1023) / 1024;     // 98
    const int CB = (N_EDGES + BCHUNK - 1) / BCHUNK; // 782
    const int UNITS = (N_NODES + 31) / 32;          // 3125
    const int LB0 = (UNITS + 3) / 4;                // 782
    const int PB2 = (N_NODES + 31) / 32;            // fallback

    // fast-path layout:
    // dinv | degc | binCnt/Start/Cursor | pairs | gAlo gAhi gBlo gBhi | agg
    const size_t PLANE_U2 = (size_t)NP * 4;                 // uint2 per plane
    const size_t FAST_BYTES =
        2ull * NP * 4 + 3ull * NBINP * 4 + (size_t)N_EDGES * 4 +
        4ull * PLANE_U2 * 8 + (size_t)NP * 16 * 4;

    if (ws_size >= FAST_BYTES) {
        float* dinv      = (float*)d_ws;                    // NP
        int*   degc      = (int*)(dinv + NP);               // NP
        int*   binCnt    = degc + NP;                       // NBINP
        int*   binStart  = binCnt + NBINP;
        int*   binCursor = binStart + NBINP;
        unsigned* pairs  = (unsigned*)(binCursor + NBINP);  // N_EDGES
        uint2* gAlo = (uint2*)(pairs + N_EDGES);
        uint2* gAhi = gAlo + PLANE_U2;
        uint2* gBlo = gAhi + PLANE_U2;
        uint2* gBhi = gBlo + PLANE_U2;
        float* agg  = (float*)(gBhi + PLANE_U2);            // NP*16

        hipMemsetAsync(binCnt, 0, NBINP * sizeof(int), stream);
        k_binhist<<<CB, 256, 0, stream>>>(col, binCnt);
        k_binscan<<<1, 1024, 0, stream>>>(binCnt, binStart, binCursor);
        k_binscatter<<<CB, 256, 0, stream>>>(row, col, binCursor, pairs);
        k_bindeg<<<NBIN, 256, 0, stream>>>(pairs, binStart, binCnt, degc, dinv);

        k_lin0_mfma<<<LB0, 256, 0, stream>>>(x, W0, b0, dinv, gAlo, gAhi, 4);

        k_push_acc<<<NBIN, 256, 0, stream>>>((const uint4*)gAlo, pairs,
                                             binStart, binCnt, agg);
        k_push_prop<<<NBIN, 256, 0, stream>>>((const uint4*)gAhi, pairs,
                                              binStart, binCnt, agg, dinv,
                                              W1, b1, gBlo, gBhi);
        k_push_acc<<<NBIN, 256, 0, stream>>>((const uint4*)gBlo, pairs,
                                             binStart, binCnt, agg);
        k_push_prop<<<NBIN, 256, 0, stream>>>((const uint4*)gBhi, pairs,
                                              binStart, binCnt, agg, dinv,
                                              W2, b2, gAlo, gAhi);
        k_push_acc<<<NBIN, 256, 0, stream>>>((const uint4*)gAlo, pairs,
                                             binStart, binCnt, agg);
        k_push_last<<<NBIN, 256, 0, stream>>>((const uint4*)gAhi, pairs,
                                              binStart, binCnt, agg, dinv,
                                              W3, b3, W4, b4, (float4*)out);
    } else {
        // ---- fallback: two-pass compact CSR, interleaved g ----
        int*   deg    = (int*)d_ws;                   // NP
        int*   rowptr = deg + NP;                     // NP
        int*   cursor = rowptr + NP;                  // NP
        int*   bsum   = cursor + NP;                  // 128
        float* dinv   = (float*)(bsum + 128);         // NP
        int*   csr    = (int*)(dinv + NP);            // N_EDGES
        uint2* gA     = (uint2*)(csr + N_EDGES);      // N*8
        uint2* gB     = gA + (size_t)N_NODES * 8;     // N*8

        hipMemsetAsync(deg, 0, (size_t)NP * 3 * sizeof(int), stream);
        k_hist<<<EB, 256, 0, stream>>>(col, deg);
        k_scan1<<<NB1024, 1024, 0, stream>>>(deg, rowptr, bsum);
        k_scan2<<<1, 128, 0, stream>>>(bsum, NB1024);
        k_scan3<<<NB256, 256, 0, stream>>>(rowptr, bsum);
        k_dinv<<<NB256, 256, 0, stream>>>(deg, 1, dinv, cursor);
        hipMemsetAsync(cursor, 0, (size_t)NP * sizeof(int), stream);
        k_scatter<<<EB, 256, 0, stream>>>(row, col, rowptr, cursor, csr);

        k_lin0_mfma<<<LB0, 256, 0, stream>>>(x, W0, b0, dinv, gA, gA + 4, 8);

        k_prop2<<<PB2, 256, 0, stream>>>(gA, csr, rowptr, deg, 1 << 30,
                                         dinv, W1, b1, gB);
        k_prop2<<<PB2, 256, 0, stream>>>(gB, csr, rowptr, deg, 1 << 30,
                                         dinv, W2, b2, gA);
        k_last2<<<PB2, 256, 0, stream>>>(gA, csr, rowptr, deg, 1 << 30,
                                         dinv, W3, b3, W4, b4, (float4*)out);
    }
}

// Round 5
// 475.289 us; speedup vs baseline: 4.3988x; 4.3988x over previous
//
#include <hip/hip_runtime.h>
#include <hip/hip_fp16.h>

#define N_NODES 100000
#define N_EDGES 3200000
#define IN_C 256
#define HID 32
#define OUT_C 64
#define CAP 80        // padded bucket capacity (Poisson(32): P(deg>80) ~ 1e-11/node)
#define NP 100032
#define BINW 256      // nodes per bin
#define BSH 8         // bin = col >> BSH
#define NBIN 391      // ceil(N_NODES / BINW)
#define BCHUNK 8192   // edges per block in hist/scatter

typedef _Float16 f16x8 __attribute__((ext_vector_type(8)));
typedef float f32x4 __attribute__((ext_vector_type(4)));

__device__ __forceinline__ float dot4(const float4 a, const float4 b) {
    return a.x * b.x + a.y * b.y + a.z * b.z + a.w * b.w;
}

// fp16x4 <-> fp32x4 pack helpers
__device__ __forceinline__ float4 h4tof4(uint2 v) {
    __half2 a = *reinterpret_cast<__half2*>(&v.x);
    __half2 b = *reinterpret_cast<__half2*>(&v.y);
    float2 fa = __half22float2(a), fb = __half22float2(b);
    return make_float4(fa.x, fa.y, fb.x, fb.y);
}
__device__ __forceinline__ uint2 f4toh4(float4 f) {
    __half2 a = __float22half2_rn(make_float2(f.x, f.y));
    __half2 b = __float22half2_rn(make_float2(f.z, f.w));
    uint2 v;
    v.x = *reinterpret_cast<unsigned int*>(&a);
    v.y = *reinterpret_cast<unsigned int*>(&b);
    return v;
}

// accumulate 8 halves (one uint4) into 8 f32
__device__ __forceinline__ void h8acc(uint4 v, float* acc) {
    __half2* p = reinterpret_cast<__half2*>(&v);
    #pragma unroll
    for (int i = 0; i < 4; ++i) {
        float2 f = __half22float2(p[i]);
        acc[2 * i] += f.x;
        acc[2 * i + 1] += f.y;
    }
}

__device__ __forceinline__ unsigned packh2(_Float16 a, _Float16 b) {
    unsigned short ua = __builtin_bit_cast(unsigned short, a);
    unsigned short ub = __builtin_bit_cast(unsigned short, b);
    return (unsigned)ua | ((unsigned)ub << 16);
}

// ---------------- graph build: binned (round-3 verified path) ----------------

// A: per-bin edge counts
__global__ __launch_bounds__(256) void k_binhist(const int* __restrict__ col,
                                                 int* __restrict__ binCnt) {
    __shared__ int h[NBIN];
    const int t = threadIdx.x;
    for (int i = t; i < NBIN; i += 256) h[i] = 0;
    __syncthreads();
    const int e0 = blockIdx.x * BCHUNK;
    const int e1 = min(N_EDGES, e0 + BCHUNK);
    for (int i = e0 + t; i < e1; i += 256)
        atomicAdd(&h[col[i] >> BSH], 1);
    __syncthreads();
    for (int i = t; i < NBIN; i += 256)
        if (h[i]) atomicAdd(&binCnt[i], h[i]);
}

// B: exclusive scan of bin counts (NBIN <= 512)
__global__ void k_binscan(const int* __restrict__ binCnt,
                          int* __restrict__ binStart, int* __restrict__ binCursor) {
    __shared__ int buf[2][512];
    const int t = threadIdx.x;
    int v = (t < NBIN) ? binCnt[t] : 0;
    buf[0][t] = v;
    __syncthreads();
    int s = 0;
    for (int off = 1; off < 512; off <<= 1) {
        int d = s ^ 1;
        int val = buf[s][t];
        if (t >= off) val += buf[s][t - off];
        buf[d][t] = val;
        __syncthreads();
        s = d;
    }
    if (t < NBIN) {
        int st = buf[s][t] - v;
        binStart[t] = st;
        binCursor[t] = st;
    }
}

// C: LDS-staged scatter of packed edges into bin-contiguous order.
// Pack: p = (row << 8) | (col & 255)
__global__ __launch_bounds__(256) void k_binscatter(const int* __restrict__ row,
                                                    const int* __restrict__ col,
                                                    int* __restrict__ binCursor,
                                                    unsigned* __restrict__ pairs) {
    __shared__ int lcnt[512];
    __shared__ int lofs[512];
    __shared__ int gbase[512];
    __shared__ int sbuf[2][256];
    __shared__ unsigned stage[BCHUNK];
    __shared__ unsigned short sbin[BCHUNK];
    const int t = threadIdx.x;
    for (int i = t; i < 512; i += 256) lcnt[i] = 0;
    __syncthreads();

    const int e0 = blockIdx.x * BCHUNK;
    const int e1 = min(N_EDGES, e0 + BCHUNK);
    const int cn = e1 - e0;

    for (int i = e0 + t; i < e1; i += 256)
        atomicAdd(&lcnt[col[i] >> BSH], 1);
    __syncthreads();

    const int a0 = lcnt[2 * t], a1 = lcnt[2 * t + 1];
    sbuf[0][t] = a0 + a1;
    __syncthreads();
    int s = 0;
    for (int off = 1; off < 256; off <<= 1) {
        int d = s ^ 1;
        int v = sbuf[s][t];
        if (t >= off) v += sbuf[s][t - off];
        sbuf[d][t] = v;
        __syncthreads();
        s = d;
    }
    const int excl = sbuf[s][t] - (a0 + a1);
    lofs[2 * t] = excl;
    lofs[2 * t + 1] = excl + a0;
    __syncthreads();

    for (int i = t; i < 512; i += 256) {
        int c = lcnt[i];
        gbase[i] = c ? atomicAdd(&binCursor[i], c) : 0;
        lcnt[i] = 0;
    }
    __syncthreads();

    for (int i = e0 + t; i < e1; i += 256) {
        int cc = col[i];
        int b = cc >> BSH;
        int p = lofs[b] + atomicAdd(&lcnt[b], 1);
        stage[p] = ((unsigned)row[i] << 8) | (unsigned)(cc & 255);
        sbin[p] = (unsigned short)b;
    }
    __syncthreads();

    for (int i = t; i < cn; i += 256) {
        int b = sbin[i];
        pairs[gbase[b] + (i - lofs[b])] = stage[i];
    }
}

// D: per-bin bucket build; also emits degc + dinv.
__global__ __launch_bounds__(256) void k_binbuild(const unsigned* __restrict__ pairs,
                                                  const int* __restrict__ binStart,
                                                  const int* __restrict__ binCnt,
                                                  int* __restrict__ bucket,
                                                  int* __restrict__ degc,
                                                  float* __restrict__ dinv) {
    __shared__ int cur[BINW];
    const int t = threadIdx.x;
    const int bin = blockIdx.x;
    const int base = bin * BINW;
    cur[t] = 0;
    __syncthreads();
    const int s = binStart[bin], cn = binCnt[bin];
    for (int i = t; i < cn; i += 256) {
        unsigned p = pairs[s + i];
        int c = (int)(p & 255u);
        int pos = atomicAdd(&cur[c], 1);
        if (pos < CAP) bucket[(size_t)(base + c) * CAP + pos] = (int)(p >> 8);
    }
    __syncthreads();
    int n = base + t;
    if (n < N_NODES) {
        int d = cur[t];
        degc[n] = d;
        dinv[n] = 1.0f / sqrtf((float)(d + 1)); // +1 self loop
    }
}

// ---------------- graph build: fallback path (two-pass compact CSR) ----------

__global__ void k_hist(const int* __restrict__ col, int* __restrict__ deg) {
    int i = blockIdx.x * 256 + threadIdx.x;
    if (i < N_EDGES) atomicAdd(&deg[col[i]], 1);
}

__global__ void k_scan1(const int* __restrict__ deg, int* __restrict__ rowptr,
                        int* __restrict__ bsum) {
    __shared__ int buf[2][1024];
    const int t = threadIdx.x, b = blockIdx.x;
    const int i = b * 1024 + t;
    int v = (i < N_NODES) ? deg[i] : 0;
    buf[0][t] = v;
    __syncthreads();
    int src = 0;
    for (int off = 1; off < 1024; off <<= 1) {
        int dst = src ^ 1;
        int val = buf[src][t];
        if (t >= off) val += buf[src][t - off];
        buf[dst][t] = val;
        __syncthreads();
        src = dst;
    }
    int incl = buf[src][t];
    if (i < N_NODES) rowptr[i] = incl - v;
    if (t == 1023) bsum[b] = incl;
}

__global__ void k_scan2(int* __restrict__ bsum, int nb) {
    __shared__ int buf[2][128];
    const int t = threadIdx.x;
    int v = (t < nb) ? bsum[t] : 0;
    buf[0][t] = v;
    __syncthreads();
    int src = 0;
    for (int off = 1; off < 128; off <<= 1) {
        int dst = src ^ 1;
        int val = buf[src][t];
        if (t >= off) val += buf[src][t - off];
        buf[dst][t] = val;
        __syncthreads();
        src = dst;
    }
    if (t < nb) bsum[t] = buf[src][t] - v;
}

__global__ void k_scan3(int* __restrict__ rowptr, const int* __restrict__ bsum) {
    int i = blockIdx.x * 256 + threadIdx.x;
    if (i < N_NODES) rowptr[i] += bsum[i >> 10];
}

__global__ void k_dinv(const int* __restrict__ cnt, int stride,
                       float* __restrict__ dinv, int* __restrict__ degc) {
    int i = blockIdx.x * 256 + threadIdx.x;
    if (i < N_NODES) {
        int d = cnt[i * stride];
        degc[i] = d;
        dinv[i] = 1.0f / sqrtf((float)(d + 1));
    }
}

__global__ void k_scatter(const int* __restrict__ row, const int* __restrict__ col,
                          const int* __restrict__ rowptr, int* __restrict__ cursor,
                          int* __restrict__ csr) {
    int i = blockIdx.x * 256 + threadIdx.x;
    if (i < N_EDGES) {
        int c = col[i];
        int pos = rowptr[c] + atomicAdd(&cursor[c], 1);
        csr[pos] = row[i];
    }
}

// ---------------- dense layer 0 (MFMA), plane-split store ----------------
// gLo/gHi: plane pointers; ns = node stride in uint2 units (4 = split planes,
// 8 with gHi = gLo+4 = legacy interleaved for fallback).
__global__ __launch_bounds__(256) void k_lin0_mfma(
        const float* __restrict__ x,
        const float* __restrict__ W0,   // [32][256]
        const float* __restrict__ b0,   // [32]
        const float* __restrict__ dinv,
        uint2* __restrict__ gLo, uint2* __restrict__ gHi, int ns) {
    __shared__ f16x8 WH[1024];   // [mt(2)][ks(8)][lane(64)] fragment-packed
    __shared__ f16x8 WL[1024];

    const int t = threadIdx.x;
    const int w = t >> 6;        // wave 0..3
    const int l = t & 63;
    const int lr = l & 15;       // within-tile row/col index
    const int lg = l >> 4;       // k-group 0..3

    for (int s = t; s < 1024; s += 256) {
        const int lane = s & 63;
        const int mtks = s >> 6;
        const int ks = mtks & 7, mt = mtks >> 3;
        const float* wr = W0 + (size_t)(mt * 16 + (lane & 15)) * IN_C
                             + ks * 32 + (lane >> 4) * 8;
        float4 a0 = *(const float4*)(wr);
        float4 a1 = *(const float4*)(wr + 4);
        float v[8] = {a0.x, a0.y, a0.z, a0.w, a1.x, a1.y, a1.z, a1.w};
        f16x8 h, lo;
        #pragma unroll
        for (int e = 0; e < 8; ++e) {
            float sv = v[e] * 16.0f;          // prescale: Wl stays f16-normal
            _Float16 hh = (_Float16)sv;
            h[e] = hh;
            lo[e] = (_Float16)(sv - (float)hh);
        }
        WH[s] = h;
        WL[s] = lo;
    }
    __syncthreads();

    const int unit = blockIdx.x * 4 + w;       // 32 nodes per unit
    if (unit * 32 >= N_NODES) return;
    const int n0 = unit * 32;

    f32x4 acc[2][2];
    #pragma unroll
    for (int mt = 0; mt < 2; ++mt)
        #pragma unroll
        for (int nt = 0; nt < 2; ++nt)
            acc[mt][nt] = (f32x4){0.f, 0.f, 0.f, 0.f};

    const float* xr0 = x + (size_t)(n0 + lr) * IN_C + lg * 8;        // nt=0
    const float* xr1 = x + (size_t)(n0 + 16 + lr) * IN_C + lg * 8;   // nt=1

    #pragma unroll
    for (int ks = 0; ks < 8; ++ks) {
        float4 u0 = *(const float4*)(xr0 + ks * 32);
        float4 u1 = *(const float4*)(xr0 + ks * 32 + 4);
        float4 v0 = *(const float4*)(xr1 + ks * 32);
        float4 v1 = *(const float4*)(xr1 + ks * 32 + 4);
        float fu[8] = {u0.x, u0.y, u0.z, u0.w, u1.x, u1.y, u1.z, u1.w};
        float fv[8] = {v0.x, v0.y, v0.z, v0.w, v1.x, v1.y, v1.z, v1.w};
        f16x8 xh0, xl0, xh1, xl1;
        #pragma unroll
        for (int e = 0; e < 8; ++e) {
            _Float16 h0 = (_Float16)fu[e];
            xh0[e] = h0;
            xl0[e] = (_Float16)(fu[e] - (float)h0);
            _Float16 h1 = (_Float16)fv[e];
            xh1[e] = h1;
            xl1[e] = (_Float16)(fv[e] - (float)h1);
        }
        #pragma unroll
        for (int mt = 0; mt < 2; ++mt) {
            f16x8 wh = WH[mt * 512 + ks * 64 + l];
            f16x8 wl = WL[mt * 512 + ks * 64 + l];
            acc[mt][0] = __builtin_amdgcn_mfma_f32_16x16x32_f16(wh, xh0, acc[mt][0], 0, 0, 0);
            acc[mt][0] = __builtin_amdgcn_mfma_f32_16x16x32_f16(wh, xl0, acc[mt][0], 0, 0, 0);
            acc[mt][0] = __builtin_amdgcn_mfma_f32_16x16x32_f16(wl, xh0, acc[mt][0], 0, 0, 0);
            acc[mt][1] = __builtin_amdgcn_mfma_f32_16x16x32_f16(wh, xh1, acc[mt][1], 0, 0, 0);
            acc[mt][1] = __builtin_amdgcn_mfma_f32_16x16x32_f16(wh, xl1, acc[mt][1], 0, 0, 0);
            acc[mt][1] = __builtin_amdgcn_mfma_f32_16x16x32_f16(wl, xh1, acc[mt][1], 0, 0, 0);
        }
    }

    #pragma unroll
    for (int nt = 0; nt < 2; ++nt) {
        const int node = n0 + nt * 16 + lr;
        const float dv = dinv[node];
        #pragma unroll
        for (int mt = 0; mt < 2; ++mt) {
            const float4 bb = *(const float4*)(b0 + mt * 16 + lg * 4);
            f32x4 a = acc[mt][nt];
            float4 r = make_float4((a[0] * 0.0625f + bb.x) * dv,
                                   (a[1] * 0.0625f + bb.y) * dv,
                                   (a[2] * 0.0625f + bb.z) * dv,
                                   (a[3] * 0.0625f + bb.w) * dv);
            uint2* dst = mt ? gHi : gLo;
            dst[(size_t)node * ns + lg] = f4toh4(r);
        }
    }
}

// ---------------- two-pass pull propagate (fast path) ----------------
// plane: [node][2] uint4 = 16 fp16 channels (3.2 MB -> per-XCD-L2-resident).
// Wave = 16 nodes, 4 lanes/node: lane lg = (part = lg&1, eo = lg>>1).
// Each lane gathers uint4 plane[r*2+part] for edges with local parity eo,
// register-accumulates, then __shfl_xor(32) combines the eo halves.

// register gather core (shared by the three kernels below)
__device__ __forceinline__ void pull_gather(const uint4* __restrict__ plane,
                                            const int* __restrict__ e, int cn,
                                            int part, int eo, float* a) {
    int j = 0;
    for (; j + 8 <= cn; j += 8) {
        int4 ea = *(const int4*)(e + j);
        int4 eb = *(const int4*)(e + j + 4);
        int r0 = eo ? ea.y : ea.x;
        int r1 = eo ? ea.w : ea.z;
        int r2 = eo ? eb.y : eb.x;
        int r3 = eo ? eb.w : eb.z;
        uint4 v0 = plane[(size_t)r0 * 2 + part];
        uint4 v1 = plane[(size_t)r1 * 2 + part];
        uint4 v2 = plane[(size_t)r2 * 2 + part];
        uint4 v3 = plane[(size_t)r3 * 2 + part];
        h8acc(v0, a); h8acc(v1, a); h8acc(v2, a); h8acc(v3, a);
    }
    for (; j + 2 <= cn; j += 2) {
        int r = e[j + eo];
        h8acc(plane[(size_t)r * 2 + part], a);
    }
    if (j < cn && eo == 0) {
        h8acc(plane[(size_t)e[j] * 2 + part], a);
    }
}

// pass 1: lo plane -> agg (f32 [node][16]); includes lo self-loop
__global__ __launch_bounds__(256) void k_agg_lo(
        const uint4* __restrict__ planeLo, const int* __restrict__ bucket,
        const int* __restrict__ degc, float* __restrict__ agg) {
    const int t = threadIdx.x;
    const int l = t & 63;
    const int tile = blockIdx.x * 4 + (t >> 6);
    const int n0 = tile * 16;
    if (n0 >= N_NODES) return;
    const int node = n0 + (l & 15);
    const int lg = l >> 4;
    const int part = lg & 1, eo = lg >> 1;

    float a[8];
    #pragma unroll
    for (int i = 0; i < 8; ++i) a[i] = 0.f;
    if (lg < 2) h8acc(planeLo[(size_t)node * 2 + part], a);   // self loop once

    const int cn = min(degc[node], CAP);
    const int* __restrict__ e = bucket + (size_t)node * CAP;
    pull_gather(planeLo, e, cn, part, eo, a);

    #pragma unroll
    for (int i = 0; i < 8; ++i) a[i] += __shfl_xor(a[i], 32, 64);

    if (lg < 2) {
        float* ap = agg + (size_t)node * 16 + part * 8;
        *(float4*)ap = make_float4(a[0], a[1], a[2], a[3]);
        *(float4*)(ap + 4) = make_float4(a[4], a[5], a[6], a[7]);
    }
}

// pass 2: hi plane gather + dense agg read + W(32x32) MFMA + plane-split store
__global__ __launch_bounds__(256) void k_prop_hi(
        const uint4* __restrict__ planeHi, const int* __restrict__ bucket,
        const int* __restrict__ degc,
        const float* __restrict__ agg, const float* __restrict__ dinv,
        const float* __restrict__ W, const float* __restrict__ b,
        uint2* __restrict__ outLo, uint2* __restrict__ outHi) {
    __shared__ f16x8 WH[128], WL[128];
    const int t = threadIdx.x;
    if (t < 128) {
        const int lane = t & 63, mt = t >> 6;
        const float* wr = W + (size_t)(mt * 16 + (lane & 15)) * HID + (lane >> 4) * 8;
        f16x8 h, lo;
        #pragma unroll
        for (int e = 0; e < 8; ++e) {
            float sv = wr[e] * 8.0f;
            _Float16 hh = (_Float16)sv;
            h[e] = hh;
            lo[e] = (_Float16)(sv - (float)hh);
        }
        WH[t] = h;
        WL[t] = lo;
    }
    __syncthreads();

    const int l = t & 63;
    const int tile = blockIdx.x * 4 + (t >> 6);
    const int n0 = tile * 16;
    if (n0 >= N_NODES) return;
    const int node = n0 + (l & 15);
    const int lg = l >> 4;
    const int part = lg & 1, eo = lg >> 1;

    float a[8];
    #pragma unroll
    for (int i = 0; i < 8; ++i) a[i] = 0.f;
    if (lg < 2) h8acc(planeHi[(size_t)node * 2 + part], a);   // self loop once

    const int cn = min(degc[node], CAP);
    const int* __restrict__ e = bucket + (size_t)node * CAP;
    pull_gather(planeHi, e, cn, part, eo, a);

    #pragma unroll
    for (int i = 0; i < 8; ++i) a[i] += __shfl_xor(a[i], 32, 64);

    // B-fragment: lanes lg<2 carry agg lo-chans; lanes lg>=2 carry hi sums
    float av[8];
    if (lg < 2) {
        const float* ap = agg + (size_t)node * 16 + lg * 8;
        float4 u0 = *(const float4*)ap;
        float4 u1 = *(const float4*)(ap + 4);
        av[0] = u0.x; av[1] = u0.y; av[2] = u0.z; av[3] = u0.w;
        av[4] = u1.x; av[5] = u1.y; av[6] = u1.z; av[7] = u1.w;
    } else {
        #pragma unroll
        for (int k = 0; k < 8; ++k) av[k] = a[k];
    }

    f16x8 bh, bl;
    #pragma unroll
    for (int i = 0; i < 8; ++i) {
        _Float16 hh = (_Float16)av[i];
        bh[i] = hh;
        bl[i] = (_Float16)(av[i] - (float)hh);
    }

    f32x4 c0 = (f32x4){0.f, 0.f, 0.f, 0.f};
    f32x4 c1 = (f32x4){0.f, 0.f, 0.f, 0.f};
    {
        f16x8 wh0 = WH[l], wl0 = WL[l];
        f16x8 wh1 = WH[64 + l], wl1 = WL[64 + l];
        c0 = __builtin_amdgcn_mfma_f32_16x16x32_f16(wh0, bh, c0, 0, 0, 0);
        c0 = __builtin_amdgcn_mfma_f32_16x16x32_f16(wh0, bl, c0, 0, 0, 0);
        c0 = __builtin_amdgcn_mfma_f32_16x16x32_f16(wl0, bh, c0, 0, 0, 0);
        c1 = __builtin_amdgcn_mfma_f32_16x16x32_f16(wh1, bh, c1, 0, 0, 0);
        c1 = __builtin_amdgcn_mfma_f32_16x16x32_f16(wh1, bl, c1, 0, 0, 0);
        c1 = __builtin_amdgcn_mfma_f32_16x16x32_f16(wl1, bh, c1, 0, 0, 0);
    }

    const float dv = dinv[node];
    #pragma unroll
    for (int mt = 0; mt < 2; ++mt) {
        const f32x4 bb = *(const f32x4*)(b + mt * 16 + lg * 4);
        f32x4 aa = mt ? c1 : c0;
        float4 r;
        r.x = fmaxf(bb[0] + dv * (aa[0] * 0.125f), 0.f) * dv;
        r.y = fmaxf(bb[1] + dv * (aa[1] * 0.125f), 0.f) * dv;
        r.z = fmaxf(bb[2] + dv * (aa[2] * 0.125f), 0.f) * dv;
        r.w = fmaxf(bb[3] + dv * (aa[3] * 0.125f), 0.f) * dv;
        uint2* dst = mt ? outHi : outLo;
        dst[(size_t)node * 4 + lg] = f4toh4(r);
    }
}

// pass 2 (last layer): hi gather + agg -> W3,relu -> shuffle -> W4 -> out
__global__ __launch_bounds__(256) void k_last_hi(
        const uint4* __restrict__ planeHi, const int* __restrict__ bucket,
        const int* __restrict__ degc,
        const float* __restrict__ agg, const float* __restrict__ dinv,
        const float* __restrict__ W3, const float* __restrict__ b3,
        const float* __restrict__ W4, const float* __restrict__ b4,
        float4* __restrict__ out4) {
    __shared__ f16x8 WH3[128], WL3[128];
    __shared__ f16x8 WH4[256], WL4[256];
    const int t = threadIdx.x;
    if (t < 128) {
        const int lane = t & 63, mt = t >> 6;
        const float* wr = W3 + (size_t)(mt * 16 + (lane & 15)) * HID + (lane >> 4) * 8;
        f16x8 h, lo;
        #pragma unroll
        for (int e = 0; e < 8; ++e) {
            float sv = wr[e] * 8.0f;
            _Float16 hh = (_Float16)sv;
            h[e] = hh;
            lo[e] = (_Float16)(sv - (float)hh);
        }
        WH3[t] = h;
        WL3[t] = lo;
    }
    {
        const int lane = t & 63, mt = t >> 6;   // mt 0..3
        const float* wr = W4 + (size_t)(mt * 16 + (lane & 15)) * HID + (lane >> 4) * 8;
        f16x8 h, lo;
        #pragma unroll
        for (int e = 0; e < 8; ++e) {
            float sv = wr[e] * 8.0f;
            _Float16 hh = (_Float16)sv;
            h[e] = hh;
            lo[e] = (_Float16)(sv - (float)hh);
        }
        WH4[t] = h;
        WL4[t] = lo;
    }
    __syncthreads();

    const int l = t & 63;
    const int tile = blockIdx.x * 4 + (t >> 6);
    const int n0 = tile * 16;
    if (n0 >= N_NODES) return;
    const int nl = l & 15;
    const int node = n0 + nl;
    const int lg = l >> 4;
    const int part = lg & 1, eo = lg >> 1;

    float a[8];
    #pragma unroll
    for (int i = 0; i < 8; ++i) a[i] = 0.f;
    if (lg < 2) h8acc(planeHi[(size_t)node * 2 + part], a);   // self loop once

    const int cn = min(degc[node], CAP);
    const int* __restrict__ e = bucket + (size_t)node * CAP;
    pull_gather(planeHi, e, cn, part, eo, a);

    #pragma unroll
    for (int i = 0; i < 8; ++i) a[i] += __shfl_xor(a[i], 32, 64);

    float av[8];
    if (lg < 2) {
        const float* ap = agg + (size_t)node * 16 + lg * 8;
        float4 u0 = *(const float4*)ap;
        float4 u1 = *(const float4*)(ap + 4);
        av[0] = u0.x; av[1] = u0.y; av[2] = u0.z; av[3] = u0.w;
        av[4] = u1.x; av[5] = u1.y; av[6] = u1.z; av[7] = u1.w;
    } else {
        #pragma unroll
        for (int k = 0; k < 8; ++k) av[k] = a[k];
    }

    f16x8 bh, bl;
    #pragma unroll
    for (int i = 0; i < 8; ++i) {
        _Float16 hh = (_Float16)av[i];
        bh[i] = hh;
        bl[i] = (_Float16)(av[i] - (float)hh);
    }

    // stage 1: y = W3 @ agg, h = relu(b3 + dv*y)
    f32x4 c0 = (f32x4){0.f, 0.f, 0.f, 0.f};
    f32x4 c1 = (f32x4){0.f, 0.f, 0.f, 0.f};
    {
        f16x8 wh0 = WH3[l], wl0 = WL3[l];
        f16x8 wh1 = WH3[64 + l], wl1 = WL3[64 + l];
        c0 = __builtin_amdgcn_mfma_f32_16x16x32_f16(wh0, bh, c0, 0, 0, 0);
        c0 = __builtin_amdgcn_mfma_f32_16x16x32_f16(wh0, bl, c0, 0, 0, 0);
        c0 = __builtin_amdgcn_mfma_f32_16x16x32_f16(wl0, bh, c0, 0, 0, 0);
        c1 = __builtin_amdgcn_mfma_f32_16x16x32_f16(wh1, bh, c1, 0, 0, 0);
        c1 = __builtin_amdgcn_mfma_f32_16x16x32_f16(wh1, bl, c1, 0, 0, 0);
        c1 = __builtin_amdgcn_mfma_f32_16x16x32_f16(wl1, bh, c1, 0, 0, 0);
    }

    const float dv = dinv[node];
    const f32x4 b3a = *(const f32x4*)(b3 + lg * 4);
    const f32x4 b3b = *(const f32x4*)(b3 + 16 + lg * 4);
    float h0[4], h1[4];
    #pragma unroll
    for (int r = 0; r < 4; ++r) {
        h0[r] = fmaxf(b3a[r] + dv * (c0[r] * 0.125f), 0.f);
        h1[r] = fmaxf(b3b[r] + dv * (c1[r] * 0.125f), 0.f);
    }

    // f16-split h, packed as half2 words
    unsigned ph[2][2], pl_[2][2];
    #pragma unroll
    for (int p = 0; p < 2; ++p) {
        _Float16 a0 = (_Float16)h0[2 * p], a1 = (_Float16)h0[2 * p + 1];
        _Float16 l0 = (_Float16)(h0[2 * p] - (float)a0);
        _Float16 l1 = (_Float16)(h0[2 * p + 1] - (float)a1);
        ph[0][p] = packh2(a0, a1);
        pl_[0][p] = packh2(l0, l1);
        _Float16 c0_ = (_Float16)h1[2 * p], c1_ = (_Float16)h1[2 * p + 1];
        _Float16 d0 = (_Float16)(h1[2 * p] - (float)c0_);
        _Float16 d1 = (_Float16)(h1[2 * p + 1] - (float)c1_);
        ph[1][p] = packh2(c0_, c1_);
        pl_[1][p] = packh2(d0, d1);
    }

    // redistribute: dest lane (nl,lg) needs h-ch lg*8..+7 of node nl
    union { unsigned u[4]; f16x8 v; } Bh, Bl;
    #pragma unroll
    for (int q = 0; q < 4; ++q) {
        int src = nl + 16 * ((lg & 1) * 2 + (q >> 1));
        unsigned a0 = (unsigned)__shfl((int)ph[0][q & 1], src, 64);
        unsigned a1 = (unsigned)__shfl((int)ph[1][q & 1], src, 64);
        Bh.u[q] = (lg >= 2) ? a1 : a0;
        unsigned c0_ = (unsigned)__shfl((int)pl_[0][q & 1], src, 64);
        unsigned c1_ = (unsigned)__shfl((int)pl_[1][q & 1], src, 64);
        Bl.u[q] = (lg >= 2) ? c1_ : c0_;
    }

    // stage 2: out = W4 @ h + b4 (4 out-ch tiles)
    f32x4 o0 = (f32x4){0.f, 0.f, 0.f, 0.f};
    f32x4 o1 = (f32x4){0.f, 0.f, 0.f, 0.f};
    f32x4 o2 = (f32x4){0.f, 0.f, 0.f, 0.f};
    f32x4 o3 = (f32x4){0.f, 0.f, 0.f, 0.f};
    {
        f16x8 wh, wl;
        wh = WH4[l];        wl = WL4[l];
        o0 = __builtin_amdgcn_mfma_f32_16x16x32_f16(wh, Bh.v, o0, 0, 0, 0);
        o0 = __builtin_amdgcn_mfma_f32_16x16x32_f16(wh, Bl.v, o0, 0, 0, 0);
        o0 = __builtin_amdgcn_mfma_f32_16x16x32_f16(wl, Bh.v, o0, 0, 0, 0);
        wh = WH4[64 + l];   wl = WL4[64 + l];
        o1 = __builtin_amdgcn_mfma_f32_16x16x32_f16(wh, Bh.v, o1, 0, 0, 0);
        o1 = __builtin_amdgcn_mfma_f32_16x16x32_f16(wh, Bl.v, o1, 0, 0, 0);
        o1 = __builtin_amdgcn_mfma_f32_16x16x32_f16(wl, Bh.v, o1, 0, 0, 0);
        wh = WH4[128 + l];  wl = WL4[128 + l];
        o2 = __builtin_amdgcn_mfma_f32_16x16x32_f16(wh, Bh.v, o2, 0, 0, 0);
        o2 = __builtin_amdgcn_mfma_f32_16x16x32_f16(wh, Bl.v, o2, 0, 0, 0);
        o2 = __builtin_amdgcn_mfma_f32_16x16x32_f16(wl, Bh.v, o2, 0, 0, 0);
        wh = WH4[192 + l];  wl = WL4[192 + l];
        o3 = __builtin_amdgcn_mfma_f32_16x16x32_f16(wh, Bh.v, o3, 0, 0, 0);
        o3 = __builtin_amdgcn_mfma_f32_16x16x32_f16(wh, Bl.v, o3, 0, 0, 0);
        o3 = __builtin_amdgcn_mfma_f32_16x16x32_f16(wl, Bh.v, o3, 0, 0, 0);
    }

    #pragma unroll
    for (int mt = 0; mt < 4; ++mt) {
        const f32x4 bb = *(const f32x4*)(b4 + mt * 16 + lg * 4);
        f32x4 aa = (mt == 0) ? o0 : (mt == 1) ? o1 : (mt == 2) ? o2 : o3;
        out4[(size_t)node * 16 + mt * 4 + lg] =
            make_float4(aa[0] * 0.125f + bb[0], aa[1] * 0.125f + bb[1],
                        aa[2] * 0.125f + bb[2], aa[3] * 0.125f + bb[3]);
    }
}

// ---------------- legacy fused propagate + linear (fallback path) ----------

__global__ __launch_bounds__(256) void k_prop2(
        const uint2* __restrict__ g2, const int* __restrict__ idx,
        const int* __restrict__ base_arr,
        const int* __restrict__ cnt_arr, int maxcnt,
        const float* __restrict__ dinv,
        const float* __restrict__ W, const float* __restrict__ b,
        uint2* __restrict__ gout2) {
    __shared__ float4 Ws[HID * 9];
    const int t = threadIdx.x;
    { int c = t >> 3, k4 = t & 7; Ws[c * 9 + k4] = ((const float4*)W)[t]; }
    __syncthreads();

    const int l = t & 7;
    const int n = blockIdx.x * 32 + (t >> 3);
    if (n >= N_NODES) return;

    int cnt = cnt_arr[n];
    if (cnt > maxcnt) cnt = maxcnt;
    const int base = base_arr[n];
    const int* __restrict__ e = idx + base;

    float4 acc = h4tof4(g2[n * 8 + l]);
    int j = 0;
    for (; j + 8 <= cnt; j += 8) {
        int r0 = e[j], r1 = e[j + 1], r2 = e[j + 2], r3 = e[j + 3];
        int r4 = e[j + 4], r5 = e[j + 5], r6 = e[j + 6], r7 = e[j + 7];
        uint2 v0 = g2[r0 * 8 + l], v1 = g2[r1 * 8 + l];
        uint2 v2 = g2[r2 * 8 + l], v3 = g2[r3 * 8 + l];
        uint2 v4 = g2[r4 * 8 + l], v5 = g2[r5 * 8 + l];
        uint2 v6 = g2[r6 * 8 + l], v7 = g2[r7 * 8 + l];
        float4 a0 = h4tof4(v0), a1 = h4tof4(v1), a2 = h4tof4(v2), a3 = h4tof4(v3);
        float4 a4 = h4tof4(v4), a5 = h4tof4(v5), a6 = h4tof4(v6), a7 = h4tof4(v7);
        acc.x += a0.x + a1.x + a2.x + a3.x + a4.x + a5.x + a6.x + a7.x;
        acc.y += a0.y + a1.y + a2.y + a3.y + a4.y + a5.y + a6.y + a7.y;
        acc.z += a0.z + a1.z + a2.z + a3.z + a4.z + a5.z + a6.z + a7.z;
        acc.w += a0.w + a1.w + a2.w + a3.w + a4.w + a5.w + a6.w + a7.w;
    }
    for (; j < cnt; ++j) {
        float4 a = h4tof4(g2[e[j] * 8 + l]);
        acc.x += a.x; acc.y += a.y; acc.z += a.z; acc.w += a.w;
    }

    const float dv = dinv[n];
    float4 y = make_float4(0.f, 0.f, 0.f, 0.f);
    #pragma unroll
    for (int m = 0; m < 8; ++m) {
        float4 sv;
        sv.x = __shfl(acc.x, m, 8);
        sv.y = __shfl(acc.y, m, 8);
        sv.z = __shfl(acc.z, m, 8);
        sv.w = __shfl(acc.w, m, 8);
        y.x += dot4(Ws[(4 * l + 0) * 9 + m], sv);
        y.y += dot4(Ws[(4 * l + 1) * 9 + m], sv);
        y.z += dot4(Ws[(4 * l + 2) * 9 + m], sv);
        y.w += dot4(Ws[(4 * l + 3) * 9 + m], sv);
    }
    const float4 bb = ((const float4*)b)[l];
    y.x = fmaxf(bb.x + dv * y.x, 0.f) * dv;
    y.y = fmaxf(bb.y + dv * y.y, 0.f) * dv;
    y.z = fmaxf(bb.z + dv * y.z, 0.f) * dv;
    y.w = fmaxf(bb.w + dv * y.w, 0.f) * dv;
    gout2[n * 8 + l] = f4toh4(y);
}

__global__ __launch_bounds__(256) void k_last2(
        const uint2* __restrict__ g2, const int* __restrict__ idx,
        const int* __restrict__ base_arr,
        const int* __restrict__ cnt_arr, int maxcnt,
        const float* __restrict__ dinv,
        const float* __restrict__ W3, const float* __restrict__ b3,
        const float* __restrict__ W4, const float* __restrict__ b4,
        float4* __restrict__ out4) {
    __shared__ float4 W3s[HID * 9];
    __shared__ float4 W4s[OUT_C * 9];
    const int t = threadIdx.x;
    { int c = t >> 3, k4 = t & 7; W3s[c * 9 + k4] = ((const float4*)W3)[t]; }
    #pragma unroll
    for (int f = t; f < 512; f += 256) {
        int c = f >> 3, k4 = f & 7;
        W4s[c * 9 + k4] = ((const float4*)W4)[f];
    }
    __syncthreads();

    const int l = t & 7;
    const int n = blockIdx.x * 32 + (t >> 3);
    if (n >= N_NODES) return;

    int cnt = cnt_arr[n];
    if (cnt > maxcnt) cnt = maxcnt;
    const int base = base_arr[n];
    const int* __restrict__ e = idx + base;

    float4 acc = h4tof4(g2[n * 8 + l]);
    int j = 0;
    for (; j + 8 <= cnt; j += 8) {
        int r0 = e[j], r1 = e[j + 1], r2 = e[j + 2], r3 = e[j + 3];
        int r4 = e[j + 4], r5 = e[j + 5], r6 = e[j + 6], r7 = e[j + 7];
        uint2 v0 = g2[r0 * 8 + l], v1 = g2[r1 * 8 + l];
        uint2 v2 = g2[r2 * 8 + l], v3 = g2[r3 * 8 + l];
        uint2 v4 = g2[r4 * 8 + l], v5 = g2[r5 * 8 + l];
        uint2 v6 = g2[r6 * 8 + l], v7 = g2[r7 * 8 + l];
        float4 a0 = h4tof4(v0), a1 = h4tof4(v1), a2 = h4tof4(v2), a3 = h4tof4(v3);
        float4 a4 = h4tof4(v4), a5 = h4tof4(v5), a6 = h4tof4(v6), a7 = h4tof4(v7);
        acc.x += a0.x + a1.x + a2.x + a3.x + a4.x + a5.x + a6.x + a7.x;
        acc.y += a0.y + a1.y + a2.y + a3.y + a4.y + a5.y + a6.y + a7.y;
        acc.z += a0.z + a1.z + a2.z + a3.z + a4.z + a5.z + a6.z + a7.z;
        acc.w += a0.w + a1.w + a2.w + a3.w + a4.w + a5.w + a6.w + a7.w;
    }
    for (; j < cnt; ++j) {
        float4 a = h4tof4(g2[e[j] * 8 + l]);
        acc.x += a.x; acc.y += a.y; acc.z += a.z; acc.w += a.w;
    }

    const float dv = dinv[n];
    float4 y = make_float4(0.f, 0.f, 0.f, 0.f);
    #pragma unroll
    for (int m = 0; m < 8; ++m) {
        float4 sv;
        sv.x = __shfl(acc.x, m, 8);
        sv.y = __shfl(acc.y, m, 8);
        sv.z = __shfl(acc.z, m, 8);
        sv.w = __shfl(acc.w, m, 8);
        y.x += dot4(W3s[(4 * l + 0) * 9 + m], sv);
        y.y += dot4(W3s[(4 * l + 1) * 9 + m], sv);
        y.z += dot4(W3s[(4 * l + 2) * 9 + m], sv);
        y.w += dot4(W3s[(4 * l + 3) * 9 + m], sv);
    }
    const float4 b3v = ((const float4*)b3)[l];
    float4 h;
    h.x = fmaxf(b3v.x + dv * y.x, 0.f);
    h.y = fmaxf(b3v.y + dv * y.y, 0.f);
    h.z = fmaxf(b3v.z + dv * y.z, 0.f);
    h.w = fmaxf(b3v.w + dv * y.w, 0.f);

    float4 ya = make_float4(0.f, 0.f, 0.f, 0.f);
    float4 yb = make_float4(0.f, 0.f, 0.f, 0.f);
    #pragma unroll
    for (int m = 0; m < 8; ++m) {
        float4 hv;
        hv.x = __shfl(h.x, m, 8);
        hv.y = __shfl(h.y, m, 8);
        hv.z = __shfl(h.z, m, 8);
        hv.w = __shfl(h.w, m, 8);
        ya.x += dot4(W4s[(4 * l + 0) * 9 + m], hv);
        ya.y += dot4(W4s[(4 * l + 1) * 9 + m], hv);
        ya.z += dot4(W4s[(4 * l + 2) * 9 + m], hv);
        ya.w += dot4(W4s[(4 * l + 3) * 9 + m], hv);
        yb.x += dot4(W4s[(32 + 4 * l + 0) * 9 + m], hv);
        yb.y += dot4(W4s[(32 + 4 * l + 1) * 9 + m], hv);
        yb.z += dot4(W4s[(32 + 4 * l + 2) * 9 + m], hv);
        yb.w += dot4(W4s[(32 + 4 * l + 3) * 9 + m], hv);
    }
    const float4 b4a = ((const float4*)b4)[l];
    const float4 b4b = ((const float4*)b4)[8 + l];
    ya.x += b4a.x; ya.y += b4a.y; ya.z += b4a.z; ya.w += b4a.w;
    yb.x += b4b.x; yb.y += b4b.y; yb.z += b4b.z; yb.w += b4b.w;
    out4[n * 16 + l] = ya;
    out4[n * 16 + 8 + l] = yb;
}

// ---------------- launcher ----------------

extern "C" void kernel_launch(void* const* d_in, const int* in_sizes, int n_in,
                              void* d_out, int out_size, void* d_ws, size_t ws_size,
                              hipStream_t stream) {
    const float* x   = (const float*)d_in[0];
    const int*   ei  = (const int*)d_in[1];
    const int*   row = ei;             // sources
    const int*   col = ei + N_EDGES;   // targets
    const float* W0 = (const float*)d_in[2];
    const float* b0 = (const float*)d_in[3];
    const float* W1 = (const float*)d_in[4];
    const float* b1 = (const float*)d_in[5];
    const float* W2 = (const float*)d_in[6];
    const float* b2 = (const float*)d_in[7];
    const float* W3 = (const float*)d_in[8];
    const float* b3 = (const float*)d_in[9];
    const float* W4 = (const float*)d_in[10];
    const float* b4 = (const float*)d_in[11];
    float* out = (float*)d_out;

    const int EB = (N_EDGES + 255) / 256;           // 12500
    const int NB256 = (N_NODES + 255) / 256;        // 391
    const int NB1024 = (N_NODES + 1023) / 1024;     // 98
    const int CB = (N_EDGES + BCHUNK - 1) / BCHUNK; // 391
    const int UNITS = (N_NODES + 31) / 32;          // 3125
    const int LB0 = (UNITS + 3) / 4;                // 782
    const int MB = (N_NODES + 63) / 64;             // 1563 (16 nodes/wave, 4 waves)
    const int PB2 = (N_NODES + 31) / 32;            // fallback

    // fast-path layout: bucket | dinv | degc | bins | union(pairs | planes+agg)
    const size_t PLANE_U2 = (size_t)NP * 4;   // uint2 per plane (32B/node)
    const size_t POST_BYTES = 4ull * PLANE_U2 * 8 + (size_t)NP * 16 * 4; // 19.2MB
    const size_t PAIR_BYTES = (size_t)N_EDGES * 4;                        // 12.8MB
    const size_t UNION_BYTES = POST_BYTES > PAIR_BYTES ? POST_BYTES : PAIR_BYTES;
    const size_t FAST_BYTES =
        (size_t)N_NODES * CAP * 4 + 2ull * NP * 4 + 3ull * 512 * 4 + UNION_BYTES;

    if (ws_size >= FAST_BYTES) {
        int*   bucket    = (int*)d_ws;                          // N_NODES*CAP
        float* dinv      = (float*)(bucket + (size_t)N_NODES * CAP);
        int*   degc      = (int*)(dinv + NP);
        int*   binCnt    = degc + NP;                           // 512
        int*   binStart  = binCnt + 512;                        // 512
        int*   binCursor = binStart + 512;                      // 512
        char*  uni       = (char*)(binCursor + 512);
        unsigned* pairs  = (unsigned*)uni;                      // build-time only
        uint2* gAlo = (uint2*)uni;                              // after build
        uint2* gAhi = gAlo + PLANE_U2;
        uint2* gBlo = gAhi + PLANE_U2;
        uint2* gBhi = gBlo + PLANE_U2;
        float* agg  = (float*)(gBhi + PLANE_U2);                // NP*16 f32

        hipMemsetAsync(binCnt, 0, 512 * sizeof(int), stream);
        k_binhist<<<CB, 256, 0, stream>>>(col, binCnt);
        k_binscan<<<1, 512, 0, stream>>>(binCnt, binStart, binCursor);
        k_binscatter<<<CB, 256, 0, stream>>>(row, col, binCursor, pairs);
        k_binbuild<<<NBIN, 256, 0, stream>>>(pairs, binStart, binCnt,
                                             bucket, degc, dinv);

        k_lin0_mfma<<<LB0, 256, 0, stream>>>(x, W0, b0, dinv, gAlo, gAhi, 4);

        k_agg_lo<<<MB, 256, 0, stream>>>((const uint4*)gAlo, bucket, degc, agg);
        k_prop_hi<<<MB, 256, 0, stream>>>((const uint4*)gAhi, bucket, degc,
                                          agg, dinv, W1, b1, gBlo, gBhi);
        k_agg_lo<<<MB, 256, 0, stream>>>((const uint4*)gBlo, bucket, degc, agg);
        k_prop_hi<<<MB, 256, 0, stream>>>((const uint4*)gBhi, bucket, degc,
                                          agg, dinv, W2, b2, gAlo, gAhi);
        k_agg_lo<<<MB, 256, 0, stream>>>((const uint4*)gAlo, bucket, degc, agg);
        k_last_hi<<<MB, 256, 0, stream>>>((const uint4*)gAhi, bucket, degc,
                                          agg, dinv, W3, b3, W4, b4,
                                          (float4*)out);
    } else {
        // ---- fallback: two-pass compact CSR, interleaved g ----
        int*   deg    = (int*)d_ws;                   // NP
        int*   rowptr = deg + NP;                     // NP
        int*   cursor = rowptr + NP;                  // NP
        int*   bsum   = cursor + NP;                  // 128
        float* dinv   = (float*)(bsum + 128);         // NP
        int*   csr    = (int*)(dinv + NP);            // N_EDGES
        uint2* gA     = (uint2*)(csr + N_EDGES);      // N*8
        uint2* gB     = gA + (size_t)N_NODES * 8;     // N*8

        hipMemsetAsync(deg, 0, (size_t)NP * 3 * sizeof(int), stream);
        k_hist<<<EB, 256, 0, stream>>>(col, deg);
        k_scan1<<<NB1024, 1024, 0, stream>>>(deg, rowptr, bsum);
        k_scan2<<<1, 128, 0, stream>>>(bsum, NB1024);
        k_scan3<<<NB256, 256, 0, stream>>>(rowptr, bsum);
        k_dinv<<<NB256, 256, 0, stream>>>(deg, 1, dinv, cursor);
        hipMemsetAsync(cursor, 0, (size_t)NP * sizeof(int), stream);
        k_scatter<<<EB, 256, 0, stream>>>(row, col, rowptr, cursor, csr);

        k_lin0_mfma<<<LB0, 256, 0, stream>>>(x, W0, b0, dinv, gA, gA + 4, 8);

        k_prop2<<<PB2, 256, 0, stream>>>(gA, csr, rowptr, deg, 1 << 30,
                                         dinv, W1, b1, gB);
        k_prop2<<<PB2, 256, 0, stream>>>(gB, csr, rowptr, deg, 1 << 30,
                                         dinv, W2, b2, gA);
        k_last2<<<PB2, 256, 0, stream>>>(gA, csr, rowptr, deg, 1 << 30,
                                         dinv, W3, b3, W4, b4, (float4*)out);
    }
}

// Round 6
// 415.949 us; speedup vs baseline: 5.0263x; 1.1427x over previous
//
#include <hip/hip_runtime.h>
#include <hip/hip_fp16.h>

#define N_NODES 100000
#define N_EDGES 3200000
#define IN_C 256
#define HID 32
#define OUT_C 64
#define CAP 80        // padded bucket capacity (Poisson(32): P(deg>80) ~ 1e-11/node)
#define NP 100032
#define BINW 256      // nodes per bin
#define BSH 8         // bin = col >> BSH
#define NBIN 391      // ceil(N_NODES / BINW)
#define BCHUNK 8192   // edges per block in hist/scatter
#define CAPB 12288    // per-bin pair-slab capacity (Poisson(8192) + 45 sigma)

typedef _Float16 f16x8 __attribute__((ext_vector_type(8)));
typedef float f32x4 __attribute__((ext_vector_type(4)));

__device__ __forceinline__ float dot4(const float4 a, const float4 b) {
    return a.x * b.x + a.y * b.y + a.z * b.z + a.w * b.w;
}

// fp16x4 <-> fp32x4 pack helpers
__device__ __forceinline__ float4 h4tof4(uint2 v) {
    __half2 a = *reinterpret_cast<__half2*>(&v.x);
    __half2 b = *reinterpret_cast<__half2*>(&v.y);
    float2 fa = __half22float2(a), fb = __half22float2(b);
    return make_float4(fa.x, fa.y, fb.x, fb.y);
}
__device__ __forceinline__ uint2 f4toh4(float4 f) {
    __half2 a = __float22half2_rn(make_float2(f.x, f.y));
    __half2 b = __float22half2_rn(make_float2(f.z, f.w));
    uint2 v;
    v.x = *reinterpret_cast<unsigned int*>(&a);
    v.y = *reinterpret_cast<unsigned int*>(&b);
    return v;
}

// accumulate 8 halves (one uint4) into 8 f32
__device__ __forceinline__ void h8acc(uint4 v, float* acc) {
    __half2* p = reinterpret_cast<__half2*>(&v);
    #pragma unroll
    for (int i = 0; i < 4; ++i) {
        float2 f = __half22float2(p[i]);
        acc[2 * i] += f.x;
        acc[2 * i + 1] += f.y;
    }
}

__device__ __forceinline__ unsigned packh2(_Float16 a, _Float16 b) {
    unsigned short ua = __builtin_bit_cast(unsigned short, a);
    unsigned short ub = __builtin_bit_cast(unsigned short, b);
    return (unsigned)ua | ((unsigned)ub << 16);
}

// ---------------- graph build: binned, single-pass reservation ----------------

// LDS-staged scatter of packed edges into per-bin slabs (bin b owns
// pairs[b*CAPB .. b*CAPB+CAPB)).  Pack: p = (row << 8) | (col & 255).
// Per chunk: LDS hist -> LDS exclusive scan -> bin-sorted staging in LDS ->
// one global atomicAdd per non-empty bin (cursor starts at 0) ->
// linear coalesced flush into the bin's slab.
__global__ __launch_bounds__(256) void k_binscatter(const int* __restrict__ row,
                                                    const int* __restrict__ col,
                                                    int* __restrict__ binCursor,
                                                    unsigned* __restrict__ pairs) {
    __shared__ int lcnt[512];
    __shared__ int lofs[512];
    __shared__ int gbase[512];
    __shared__ int sbuf[2][256];
    __shared__ unsigned stage[BCHUNK];
    __shared__ unsigned short sbin[BCHUNK];
    const int t = threadIdx.x;
    for (int i = t; i < 512; i += 256) lcnt[i] = 0;
    __syncthreads();

    const int e0 = blockIdx.x * BCHUNK;
    const int e1 = min(N_EDGES, e0 + BCHUNK);
    const int cn = e1 - e0;

    for (int i = e0 + t; i < e1; i += 256)
        atomicAdd(&lcnt[col[i] >> BSH], 1);
    __syncthreads();

    const int a0 = lcnt[2 * t], a1 = lcnt[2 * t + 1];
    sbuf[0][t] = a0 + a1;
    __syncthreads();
    int s = 0;
    for (int off = 1; off < 256; off <<= 1) {
        int d = s ^ 1;
        int v = sbuf[s][t];
        if (t >= off) v += sbuf[s][t - off];
        sbuf[d][t] = v;
        __syncthreads();
        s = d;
    }
    const int excl = sbuf[s][t] - (a0 + a1);
    lofs[2 * t] = excl;
    lofs[2 * t + 1] = excl + a0;
    __syncthreads();

    for (int i = t; i < 512; i += 256) {
        int c = lcnt[i];
        gbase[i] = c ? atomicAdd(&binCursor[i], c) : 0;
        lcnt[i] = 0;
    }
    __syncthreads();

    for (int i = e0 + t; i < e1; i += 256) {
        int cc = col[i];
        int b = cc >> BSH;
        int p = lofs[b] + atomicAdd(&lcnt[b], 1);
        stage[p] = ((unsigned)row[i] << 8) | (unsigned)(cc & 255);
        sbin[p] = (unsigned short)b;
    }
    __syncthreads();

    for (int i = t; i < cn; i += 256) {
        int b = sbin[i];
        int pos = gbase[b] + (i - lofs[b]);
        if (pos < CAPB)
            pairs[(size_t)b * CAPB + pos] = stage[i];
    }
}

// per-bin bucket build from the bin's slab; also emits degc + dinv.
__global__ __launch_bounds__(256) void k_binbuild(const unsigned* __restrict__ pairs,
                                                  const int* __restrict__ binCursor,
                                                  int* __restrict__ bucket,
                                                  int* __restrict__ degc,
                                                  float* __restrict__ dinv) {
    __shared__ int cur[BINW];
    const int t = threadIdx.x;
    const int bin = blockIdx.x;
    const int base = bin * BINW;
    cur[t] = 0;
    __syncthreads();
    const unsigned* __restrict__ slab = pairs + (size_t)bin * CAPB;
    const int cn = min(binCursor[bin], CAPB);
    for (int i = t; i < cn; i += 256) {
        unsigned p = slab[i];
        int c = (int)(p & 255u);
        int pos = atomicAdd(&cur[c], 1);
        if (pos < CAP) bucket[(size_t)(base + c) * CAP + pos] = (int)(p >> 8);
    }
    __syncthreads();
    int n = base + t;
    if (n < N_NODES) {
        int d = cur[t];
        degc[n] = d;
        dinv[n] = 1.0f / sqrtf((float)(d + 1)); // +1 self loop
    }
}

// ---------------- graph build: fallback path (two-pass compact CSR) ----------

__global__ void k_hist(const int* __restrict__ col, int* __restrict__ deg) {
    int i = blockIdx.x * 256 + threadIdx.x;
    if (i < N_EDGES) atomicAdd(&deg[col[i]], 1);
}

__global__ void k_scan1(const int* __restrict__ deg, int* __restrict__ rowptr,
                        int* __restrict__ bsum) {
    __shared__ int buf[2][1024];
    const int t = threadIdx.x, b = blockIdx.x;
    const int i = b * 1024 + t;
    int v = (i < N_NODES) ? deg[i] : 0;
    buf[0][t] = v;
    __syncthreads();
    int src = 0;
    for (int off = 1; off < 1024; off <<= 1) {
        int dst = src ^ 1;
        int val = buf[src][t];
        if (t >= off) val += buf[src][t - off];
        buf[dst][t] = val;
        __syncthreads();
        src = dst;
    }
    int incl = buf[src][t];
    if (i < N_NODES) rowptr[i] = incl - v;
    if (t == 1023) bsum[b] = incl;
}

__global__ void k_scan2(int* __restrict__ bsum, int nb) {
    __shared__ int buf[2][128];
    const int t = threadIdx.x;
    int v = (t < nb) ? bsum[t] : 0;
    buf[0][t] = v;
    __syncthreads();
    int src = 0;
    for (int off = 1; off < 128; off <<= 1) {
        int dst = src ^ 1;
        int val = buf[src][t];
        if (t >= off) val += buf[src][t - off];
        buf[dst][t] = val;
        __syncthreads();
        src = dst;
    }
    if (t < nb) bsum[t] = buf[src][t] - v;
}

__global__ void k_scan3(int* __restrict__ rowptr, const int* __restrict__ bsum) {
    int i = blockIdx.x * 256 + threadIdx.x;
    if (i < N_NODES) rowptr[i] += bsum[i >> 10];
}

__global__ void k_dinv(const int* __restrict__ cnt, int stride,
                       float* __restrict__ dinv, int* __restrict__ degc) {
    int i = blockIdx.x * 256 + threadIdx.x;
    if (i < N_NODES) {
        int d = cnt[i * stride];
        degc[i] = d;
        dinv[i] = 1.0f / sqrtf((float)(d + 1));
    }
}

__global__ void k_scatter(const int* __restrict__ row, const int* __restrict__ col,
                          const int* __restrict__ rowptr, int* __restrict__ cursor,
                          int* __restrict__ csr) {
    int i = blockIdx.x * 256 + threadIdx.x;
    if (i < N_EDGES) {
        int c = col[i];
        int pos = rowptr[c] + atomicAdd(&cursor[c], 1);
        csr[pos] = row[i];
    }
}

// ---------------- dense layer 0 (MFMA) ----------------
__global__ __launch_bounds__(256) void k_lin0_mfma(
        const float* __restrict__ x,
        const float* __restrict__ W0,   // [32][256]
        const float* __restrict__ b0,   // [32]
        const float* __restrict__ dinv,
        uint2* __restrict__ g2) {
    __shared__ f16x8 WH[1024];   // [mt(2)][ks(8)][lane(64)] fragment-packed
    __shared__ f16x8 WL[1024];

    const int t = threadIdx.x;
    const int w = t >> 6;        // wave 0..3
    const int l = t & 63;
    const int lr = l & 15;       // within-tile row/col index
    const int lg = l >> 4;       // k-group 0..3

    for (int s = t; s < 1024; s += 256) {
        const int lane = s & 63;
        const int mtks = s >> 6;
        const int ks = mtks & 7, mt = mtks >> 3;
        const float* wr = W0 + (size_t)(mt * 16 + (lane & 15)) * IN_C
                             + ks * 32 + (lane >> 4) * 8;
        float4 a0 = *(const float4*)(wr);
        float4 a1 = *(const float4*)(wr + 4);
        float v[8] = {a0.x, a0.y, a0.z, a0.w, a1.x, a1.y, a1.z, a1.w};
        f16x8 h, lo;
        #pragma unroll
        for (int e = 0; e < 8; ++e) {
            float sv = v[e] * 16.0f;          // prescale: Wl stays f16-normal
            _Float16 hh = (_Float16)sv;
            h[e] = hh;
            lo[e] = (_Float16)(sv - (float)hh);
        }
        WH[s] = h;
        WL[s] = lo;
    }
    __syncthreads();

    const int unit = blockIdx.x * 4 + w;       // 32 nodes per unit
    if (unit * 32 >= N_NODES) return;
    const int n0 = unit * 32;

    f32x4 acc[2][2];
    #pragma unroll
    for (int mt = 0; mt < 2; ++mt)
        #pragma unroll
        for (int nt = 0; nt < 2; ++nt)
            acc[mt][nt] = (f32x4){0.f, 0.f, 0.f, 0.f};

    const float* xr0 = x + (size_t)(n0 + lr) * IN_C + lg * 8;        // nt=0
    const float* xr1 = x + (size_t)(n0 + 16 + lr) * IN_C + lg * 8;   // nt=1

    #pragma unroll
    for (int ks = 0; ks < 8; ++ks) {
        float4 u0 = *(const float4*)(xr0 + ks * 32);
        float4 u1 = *(const float4*)(xr0 + ks * 32 + 4);
        float4 v0 = *(const float4*)(xr1 + ks * 32);
        float4 v1 = *(const float4*)(xr1 + ks * 32 + 4);
        float fu[8] = {u0.x, u0.y, u0.z, u0.w, u1.x, u1.y, u1.z, u1.w};
        float fv[8] = {v0.x, v0.y, v0.z, v0.w, v1.x, v1.y, v1.z, v1.w};
        f16x8 xh0, xl0, xh1, xl1;
        #pragma unroll
        for (int e = 0; e < 8; ++e) {
            _Float16 h0 = (_Float16)fu[e];
            xh0[e] = h0;
            xl0[e] = (_Float16)(fu[e] - (float)h0);
            _Float16 h1 = (_Float16)fv[e];
            xh1[e] = h1;
            xl1[e] = (_Float16)(fv[e] - (float)h1);
        }
        #pragma unroll
        for (int mt = 0; mt < 2; ++mt) {
            f16x8 wh = WH[mt * 512 + ks * 64 + l];
            f16x8 wl = WL[mt * 512 + ks * 64 + l];
            acc[mt][0] = __builtin_amdgcn_mfma_f32_16x16x32_f16(wh, xh0, acc[mt][0], 0, 0, 0);
            acc[mt][0] = __builtin_amdgcn_mfma_f32_16x16x32_f16(wh, xl0, acc[mt][0], 0, 0, 0);
            acc[mt][0] = __builtin_amdgcn_mfma_f32_16x16x32_f16(wl, xh0, acc[mt][0], 0, 0, 0);
            acc[mt][1] = __builtin_amdgcn_mfma_f32_16x16x32_f16(wh, xh1, acc[mt][1], 0, 0, 0);
            acc[mt][1] = __builtin_amdgcn_mfma_f32_16x16x32_f16(wh, xl1, acc[mt][1], 0, 0, 0);
            acc[mt][1] = __builtin_amdgcn_mfma_f32_16x16x32_f16(wl, xh1, acc[mt][1], 0, 0, 0);
        }
    }

    #pragma unroll
    for (int nt = 0; nt < 2; ++nt) {
        const int node = n0 + nt * 16 + lr;
        const float dv = dinv[node];
        #pragma unroll
        for (int mt = 0; mt < 2; ++mt) {
            const float4 bb = *(const float4*)(b0 + mt * 16 + lg * 4);
            f32x4 a = acc[mt][nt];
            float4 r = make_float4((a[0] * 0.0625f + bb.x) * dv,
                                   (a[1] * 0.0625f + bb.y) * dv,
                                   (a[2] * 0.0625f + bb.z) * dv,
                                   (a[3] * 0.0625f + bb.w) * dv);
            g2[(size_t)node * 8 + mt * 4 + lg] = f4toh4(r);
        }
    }
}

// ---------------- MFMA propagate+linear (fast path) ----------------
// Wave = 16 nodes, 4 lanes/node. Lane l: node = n0 + (l&15), channels
// (l>>4)*8 .. +7 (one uint4 of g2 per gather = MFMA B-fragment layout).
// Aggregate in fp32, f16-split, then y = W(32x32) @ agg via 6 split-MFMAs.
__global__ __launch_bounds__(256) void k_prop_mfma(
        const uint2* __restrict__ g2, const int* __restrict__ idx,
        const int* __restrict__ cnt_arr,
        const float* __restrict__ dinv,
        const float* __restrict__ W, const float* __restrict__ b,
        uint2* __restrict__ gout2) {
    __shared__ f16x8 WH[128], WL[128];   // A-fragments, 2 out-ch tiles
    const int t = threadIdx.x;
    if (t < 128) {
        const int lane = t & 63, mt = t >> 6;
        const float* wr = W + (size_t)(mt * 16 + (lane & 15)) * HID + (lane >> 4) * 8;
        f16x8 h, lo;
        #pragma unroll
        for (int e = 0; e < 8; ++e) {
            float sv = wr[e] * 8.0f;          // prescale x8: Wl stays f16-normal
            _Float16 hh = (_Float16)sv;
            h[e] = hh;
            lo[e] = (_Float16)(sv - (float)hh);
        }
        WH[t] = h;
        WL[t] = lo;
    }
    __syncthreads();

    const int l = t & 63;
    const int tile = blockIdx.x * 4 + (t >> 6);
    const int n0 = tile * 16;
    if (n0 >= N_NODES) return;
    const int node = n0 + (l & 15);
    const int lg = l >> 4;

    const uint4* __restrict__ g4 = (const uint4*)g2;
    float acc[8];
    #pragma unroll
    for (int i = 0; i < 8; ++i) acc[i] = 0.f;
    h8acc(g4[(size_t)node * 4 + lg], acc);     // self loop

    const int cn = min(cnt_arr[node], CAP);
    const int* __restrict__ e = idx + (size_t)node * CAP;
    int j = 0;
    for (; j + 8 <= cn; j += 8) {
        int4 ra = *(const int4*)(e + j);
        int4 rb = *(const int4*)(e + j + 4);
        uint4 v0 = g4[(size_t)ra.x * 4 + lg];
        uint4 v1 = g4[(size_t)ra.y * 4 + lg];
        uint4 v2 = g4[(size_t)ra.z * 4 + lg];
        uint4 v3 = g4[(size_t)ra.w * 4 + lg];
        uint4 v4 = g4[(size_t)rb.x * 4 + lg];
        uint4 v5 = g4[(size_t)rb.y * 4 + lg];
        uint4 v6 = g4[(size_t)rb.z * 4 + lg];
        uint4 v7 = g4[(size_t)rb.w * 4 + lg];
        h8acc(v0, acc); h8acc(v1, acc); h8acc(v2, acc); h8acc(v3, acc);
        h8acc(v4, acc); h8acc(v5, acc); h8acc(v6, acc); h8acc(v7, acc);
    }
    for (; j < cn; ++j) h8acc(g4[(size_t)e[j] * 4 + lg], acc);

    // f16 split of aggregate (B-fragment)
    f16x8 bh, bl;
    #pragma unroll
    for (int i = 0; i < 8; ++i) {
        _Float16 hh = (_Float16)acc[i];
        bh[i] = hh;
        bl[i] = (_Float16)(acc[i] - (float)hh);
    }

    f32x4 c0 = (f32x4){0.f, 0.f, 0.f, 0.f};
    f32x4 c1 = (f32x4){0.f, 0.f, 0.f, 0.f};
    {
        f16x8 wh0 = WH[l], wl0 = WL[l];
        f16x8 wh1 = WH[64 + l], wl1 = WL[64 + l];
        c0 = __builtin_amdgcn_mfma_f32_16x16x32_f16(wh0, bh, c0, 0, 0, 0);
        c0 = __builtin_amdgcn_mfma_f32_16x16x32_f16(wh0, bl, c0, 0, 0, 0);
        c0 = __builtin_amdgcn_mfma_f32_16x16x32_f16(wl0, bh, c0, 0, 0, 0);
        c1 = __builtin_amdgcn_mfma_f32_16x16x32_f16(wh1, bh, c1, 0, 0, 0);
        c1 = __builtin_amdgcn_mfma_f32_16x16x32_f16(wh1, bl, c1, 0, 0, 0);
        c1 = __builtin_amdgcn_mfma_f32_16x16x32_f16(wl1, bh, c1, 0, 0, 0);
    }

    const float dv = dinv[node];
    #pragma unroll
    for (int mt = 0; mt < 2; ++mt) {
        const f32x4 bb = *(const f32x4*)(b + mt * 16 + lg * 4);
        f32x4 a = mt ? c1 : c0;
        float4 r;
        r.x = fmaxf(bb[0] + dv * (a[0] * 0.125f), 0.f) * dv;
        r.y = fmaxf(bb[1] + dv * (a[1] * 0.125f), 0.f) * dv;
        r.z = fmaxf(bb[2] + dv * (a[2] * 0.125f), 0.f) * dv;
        r.w = fmaxf(bb[3] + dv * (a[3] * 0.125f), 0.f) * dv;
        gout2[(size_t)node * 8 + mt * 4 + lg] = f4toh4(r);
    }
}

// Last layer: agg -> (W3,relu) -> h -> (W4) -> out(64, fp32)
__global__ __launch_bounds__(256) void k_last_mfma(
        const uint2* __restrict__ g2, const int* __restrict__ idx,
        const int* __restrict__ cnt_arr,
        const float* __restrict__ dinv,
        const float* __restrict__ W3, const float* __restrict__ b3,
        const float* __restrict__ W4, const float* __restrict__ b4,
        float4* __restrict__ out4) {
    __shared__ f16x8 WH3[128], WL3[128];
    __shared__ f16x8 WH4[256], WL4[256];
    const int t = threadIdx.x;
    if (t < 128) {
        const int lane = t & 63, mt = t >> 6;
        const float* wr = W3 + (size_t)(mt * 16 + (lane & 15)) * HID + (lane >> 4) * 8;
        f16x8 h, lo;
        #pragma unroll
        for (int e = 0; e < 8; ++e) {
            float sv = wr[e] * 8.0f;
            _Float16 hh = (_Float16)sv;
            h[e] = hh;
            lo[e] = (_Float16)(sv - (float)hh);
        }
        WH3[t] = h;
        WL3[t] = lo;
    }
    {
        const int lane = t & 63, mt = t >> 6;   // mt 0..3
        const float* wr = W4 + (size_t)(mt * 16 + (lane & 15)) * HID + (lane >> 4) * 8;
        f16x8 h, lo;
        #pragma unroll
        for (int e = 0; e < 8; ++e) {
            float sv = wr[e] * 8.0f;
            _Float16 hh = (_Float16)sv;
            h[e] = hh;
            lo[e] = (_Float16)(sv - (float)hh);
        }
        WH4[t] = h;
        WL4[t] = lo;
    }
    __syncthreads();

    const int l = t & 63;
    const int tile = blockIdx.x * 4 + (t >> 6);
    const int n0 = tile * 16;
    if (n0 >= N_NODES) return;
    const int nl = l & 15;
    const int node = n0 + nl;
    const int lg = l >> 4;

    const uint4* __restrict__ g4 = (const uint4*)g2;
    float acc[8];
    #pragma unroll
    for (int i = 0; i < 8; ++i) acc[i] = 0.f;
    h8acc(g4[(size_t)node * 4 + lg], acc);     // self loop

    const int cn = min(cnt_arr[node], CAP);
    const int* __restrict__ e = idx + (size_t)node * CAP;
    int j = 0;
    for (; j + 8 <= cn; j += 8) {
        int4 ra = *(const int4*)(e + j);
        int4 rb = *(const int4*)(e + j + 4);
        uint4 v0 = g4[(size_t)ra.x * 4 + lg];
        uint4 v1 = g4[(size_t)ra.y * 4 + lg];
        uint4 v2 = g4[(size_t)ra.z * 4 + lg];
        uint4 v3 = g4[(size_t)ra.w * 4 + lg];
        uint4 v4 = g4[(size_t)rb.x * 4 + lg];
        uint4 v5 = g4[(size_t)rb.y * 4 + lg];
        uint4 v6 = g4[(size_t)rb.z * 4 + lg];
        uint4 v7 = g4[(size_t)rb.w * 4 + lg];
        h8acc(v0, acc); h8acc(v1, acc); h8acc(v2, acc); h8acc(v3, acc);
        h8acc(v4, acc); h8acc(v5, acc); h8acc(v6, acc); h8acc(v7, acc);
    }
    for (; j < cn; ++j) h8acc(g4[(size_t)e[j] * 4 + lg], acc);

    f16x8 bh, bl;
    #pragma unroll
    for (int i = 0; i < 8; ++i) {
        _Float16 hh = (_Float16)acc[i];
        bh[i] = hh;
        bl[i] = (_Float16)(acc[i] - (float)hh);
    }

    // stage 1: y = W3 @ agg, h = relu(b3 + dv*y)
    f32x4 c0 = (f32x4){0.f, 0.f, 0.f, 0.f};
    f32x4 c1 = (f32x4){0.f, 0.f, 0.f, 0.f};
    {
        f16x8 wh0 = WH3[l], wl0 = WL3[l];
        f16x8 wh1 = WH3[64 + l], wl1 = WL3[64 + l];
        c0 = __builtin_amdgcn_mfma_f32_16x16x32_f16(wh0, bh, c0, 0, 0, 0);
        c0 = __builtin_amdgcn_mfma_f32_16x16x32_f16(wh0, bl, c0, 0, 0, 0);
        c0 = __builtin_amdgcn_mfma_f32_16x16x32_f16(wl0, bh, c0, 0, 0, 0);
        c1 = __builtin_amdgcn_mfma_f32_16x16x32_f16(wh1, bh, c1, 0, 0, 0);
        c1 = __builtin_amdgcn_mfma_f32_16x16x32_f16(wh1, bl, c1, 0, 0, 0);
        c1 = __builtin_amdgcn_mfma_f32_16x16x32_f16(wl1, bh, c1, 0, 0, 0);
    }

    const float dv = dinv[node];
    const f32x4 b3a = *(const f32x4*)(b3 + lg * 4);
    const f32x4 b3b = *(const f32x4*)(b3 + 16 + lg * 4);
    float h0[4], h1[4];
    #pragma unroll
    for (int r = 0; r < 4; ++r) {
        h0[r] = fmaxf(b3a[r] + dv * (c0[r] * 0.125f), 0.f);
        h1[r] = fmaxf(b3b[r] + dv * (c1[r] * 0.125f), 0.f);
    }

    // f16-split h, packed as half2 words: ph[mt][p] = ch (mt*16+lg*4+2p, +1)
    unsigned ph[2][2], pl_[2][2];
    #pragma unroll
    for (int p = 0; p < 2; ++p) {
        _Float16 a0 = (_Float16)h0[2 * p], a1 = (_Float16)h0[2 * p + 1];
        _Float16 l0 = (_Float16)(h0[2 * p] - (float)a0);
        _Float16 l1 = (_Float16)(h0[2 * p + 1] - (float)a1);
        ph[0][p] = packh2(a0, a1);
        pl_[0][p] = packh2(l0, l1);
        _Float16 c0_ = (_Float16)h1[2 * p], c1_ = (_Float16)h1[2 * p + 1];
        _Float16 d0 = (_Float16)(h1[2 * p] - (float)c0_);
        _Float16 d1 = (_Float16)(h1[2 * p + 1] - (float)c1_);
        ph[1][p] = packh2(c0_, c1_);
        pl_[1][p] = packh2(d0, d1);
    }

    // redistribute: dest lane (nl,lg) needs h-ch lg*8..+7 of node nl.
    union { unsigned u[4]; f16x8 v; } Bh, Bl;
    #pragma unroll
    for (int q = 0; q < 4; ++q) {
        int src = nl + 16 * ((lg & 1) * 2 + (q >> 1));
        unsigned a0 = (unsigned)__shfl((int)ph[0][q & 1], src, 64);
        unsigned a1 = (unsigned)__shfl((int)ph[1][q & 1], src, 64);
        Bh.u[q] = (lg >= 2) ? a1 : a0;
        unsigned c0_ = (unsigned)__shfl((int)pl_[0][q & 1], src, 64);
        unsigned c1_ = (unsigned)__shfl((int)pl_[1][q & 1], src, 64);
        Bl.u[q] = (lg >= 2) ? c1_ : c0_;
    }

    // stage 2: out = W4 @ h + b4 (4 out-ch tiles)
    f32x4 o0 = (f32x4){0.f, 0.f, 0.f, 0.f};
    f32x4 o1 = (f32x4){0.f, 0.f, 0.f, 0.f};
    f32x4 o2 = (f32x4){0.f, 0.f, 0.f, 0.f};
    f32x4 o3 = (f32x4){0.f, 0.f, 0.f, 0.f};
    {
        f16x8 wh, wl;
        wh = WH4[l];        wl = WL4[l];
        o0 = __builtin_amdgcn_mfma_f32_16x16x32_f16(wh, Bh.v, o0, 0, 0, 0);
        o0 = __builtin_amdgcn_mfma_f32_16x16x32_f16(wh, Bl.v, o0, 0, 0, 0);
        o0 = __builtin_amdgcn_mfma_f32_16x16x32_f16(wl, Bh.v, o0, 0, 0, 0);
        wh = WH4[64 + l];   wl = WL4[64 + l];
        o1 = __builtin_amdgcn_mfma_f32_16x16x32_f16(wh, Bh.v, o1, 0, 0, 0);
        o1 = __builtin_amdgcn_mfma_f32_16x16x32_f16(wh, Bl.v, o1, 0, 0, 0);
        o1 = __builtin_amdgcn_mfma_f32_16x16x32_f16(wl, Bh.v, o1, 0, 0, 0);
        wh = WH4[128 + l];  wl = WL4[128 + l];
        o2 = __builtin_amdgcn_mfma_f32_16x16x32_f16(wh, Bh.v, o2, 0, 0, 0);
        o2 = __builtin_amdgcn_mfma_f32_16x16x32_f16(wh, Bl.v, o2, 0, 0, 0);
        o2 = __builtin_amdgcn_mfma_f32_16x16x32_f16(wl, Bh.v, o2, 0, 0, 0);
        wh = WH4[192 + l];  wl = WL4[192 + l];
        o3 = __builtin_amdgcn_mfma_f32_16x16x32_f16(wh, Bh.v, o3, 0, 0, 0);
        o3 = __builtin_amdgcn_mfma_f32_16x16x32_f16(wh, Bl.v, o3, 0, 0, 0);
        o3 = __builtin_amdgcn_mfma_f32_16x16x32_f16(wl, Bh.v, o3, 0, 0, 0);
    }

    #pragma unroll
    for (int mt = 0; mt < 4; ++mt) {
        const f32x4 bb = *(const f32x4*)(b4 + mt * 16 + lg * 4);
        f32x4 a = (mt == 0) ? o0 : (mt == 1) ? o1 : (mt == 2) ? o2 : o3;
        out4[(size_t)node * 16 + mt * 4 + lg] =
            make_float4(a[0] * 0.125f + bb[0], a[1] * 0.125f + bb[1],
                        a[2] * 0.125f + bb[2], a[3] * 0.125f + bb[3]);
    }
}

// ---------------- legacy fused propagate + linear (fallback path) ----------

__global__ __launch_bounds__(256) void k_prop2(
        const uint2* __restrict__ g2, const int* __restrict__ idx,
        const int* __restrict__ base_arr,
        const int* __restrict__ cnt_arr, int maxcnt,
        const float* __restrict__ dinv,
        const float* __restrict__ W, const float* __restrict__ b,
        uint2* __restrict__ gout2) {
    __shared__ float4 Ws[HID * 9];
    const int t = threadIdx.x;
    { int c = t >> 3, k4 = t & 7; Ws[c * 9 + k4] = ((const float4*)W)[t]; }
    __syncthreads();

    const int l = t & 7;
    const int n = blockIdx.x * 32 + (t >> 3);
    if (n >= N_NODES) return;

    int cnt = cnt_arr[n];
    if (cnt > maxcnt) cnt = maxcnt;
    const int base = base_arr[n];
    const int* __restrict__ e = idx + base;

    float4 acc = h4tof4(g2[n * 8 + l]);
    int j = 0;
    for (; j + 8 <= cnt; j += 8) {
        int r0 = e[j], r1 = e[j + 1], r2 = e[j + 2], r3 = e[j + 3];
        int r4 = e[j + 4], r5 = e[j + 5], r6 = e[j + 6], r7 = e[j + 7];
        uint2 v0 = g2[r0 * 8 + l], v1 = g2[r1 * 8 + l];
        uint2 v2 = g2[r2 * 8 + l], v3 = g2[r3 * 8 + l];
        uint2 v4 = g2[r4 * 8 + l], v5 = g2[r5 * 8 + l];
        uint2 v6 = g2[r6 * 8 + l], v7 = g2[r7 * 8 + l];
        float4 a0 = h4tof4(v0), a1 = h4tof4(v1), a2 = h4tof4(v2), a3 = h4tof4(v3);
        float4 a4 = h4tof4(v4), a5 = h4tof4(v5), a6 = h4tof4(v6), a7 = h4tof4(v7);
        acc.x += a0.x + a1.x + a2.x + a3.x + a4.x + a5.x + a6.x + a7.x;
        acc.y += a0.y + a1.y + a2.y + a3.y + a4.y + a5.y + a6.y + a7.y;
        acc.z += a0.z + a1.z + a2.z + a3.z + a4.z + a5.z + a6.z + a7.z;
        acc.w += a0.w + a1.w + a2.w + a3.w + a4.w + a5.w + a6.w + a7.w;
    }
    for (; j < cnt; ++j) {
        float4 a = h4tof4(g2[e[j] * 8 + l]);
        acc.x += a.x; acc.y += a.y; acc.z += a.z; acc.w += a.w;
    }

    const float dv = dinv[n];
    float4 y = make_float4(0.f, 0.f, 0.f, 0.f);
    #pragma unroll
    for (int m = 0; m < 8; ++m) {
        float4 sv;
        sv.x = __shfl(acc.x, m, 8);
        sv.y = __shfl(acc.y, m, 8);
        sv.z = __shfl(acc.z, m, 8);
        sv.w = __shfl(acc.w, m, 8);
        y.x += dot4(Ws[(4 * l + 0) * 9 + m], sv);
        y.y += dot4(Ws[(4 * l + 1) * 9 + m], sv);
        y.z += dot4(Ws[(4 * l + 2) * 9 + m], sv);
        y.w += dot4(Ws[(4 * l + 3) * 9 + m], sv);
    }
    const float4 bb = ((const float4*)b)[l];
    y.x = fmaxf(bb.x + dv * y.x, 0.f) * dv;
    y.y = fmaxf(bb.y + dv * y.y, 0.f) * dv;
    y.z = fmaxf(bb.z + dv * y.z, 0.f) * dv;
    y.w = fmaxf(bb.w + dv * y.w, 0.f) * dv;
    gout2[n * 8 + l] = f4toh4(y);
}

__global__ __launch_bounds__(256) void k_last2(
        const uint2* __restrict__ g2, const int* __restrict__ idx,
        const int* __restrict__ base_arr,
        const int* __restrict__ cnt_arr, int maxcnt,
        const float* __restrict__ dinv,
        const float* __restrict__ W3, const float* __restrict__ b3,
        const float* __restrict__ W4, const float* __restrict__ b4,
        float4* __restrict__ out4) {
    __shared__ float4 W3s[HID * 9];
    __shared__ float4 W4s[OUT_C * 9];
    const int t = threadIdx.x;
    { int c = t >> 3, k4 = t & 7; W3s[c * 9 + k4] = ((const float4*)W3)[t]; }
    #pragma unroll
    for (int f = t; f < 512; f += 256) {
        int c = f >> 3, k4 = f & 7;
        W4s[c * 9 + k4] = ((const float4*)W4)[f];
    }
    __syncthreads();

    const int l = t & 7;
    const int n = blockIdx.x * 32 + (t >> 3);
    if (n >= N_NODES) return;

    int cnt = cnt_arr[n];
    if (cnt > maxcnt) cnt = maxcnt;
    const int base = base_arr[n];
    const int* __restrict__ e = idx + base;

    float4 acc = h4tof4(g2[n * 8 + l]);
    int j = 0;
    for (; j + 8 <= cnt; j += 8) {
        int r0 = e[j], r1 = e[j + 1], r2 = e[j + 2], r3 = e[j + 3];
        int r4 = e[j + 4], r5 = e[j + 5], r6 = e[j + 6], r7 = e[j + 7];
        uint2 v0 = g2[r0 * 8 + l], v1 = g2[r1 * 8 + l];
        uint2 v2 = g2[r2 * 8 + l], v3 = g2[r3 * 8 + l];
        uint2 v4 = g2[r4 * 8 + l], v5 = g2[r5 * 8 + l];
        uint2 v6 = g2[r6 * 8 + l], v7 = g2[r7 * 8 + l];
        float4 a0 = h4tof4(v0), a1 = h4tof4(v1), a2 = h4tof4(v2), a3 = h4tof4(v3);
        float4 a4 = h4tof4(v4), a5 = h4tof4(v5), a6 = h4tof4(v6), a7 = h4tof4(v7);
        acc.x += a0.x + a1.x + a2.x + a3.x + a4.x + a5.x + a6.x + a7.x;
        acc.y += a0.y + a1.y + a2.y + a3.y + a4.y + a5.y + a6.y + a7.y;
        acc.z += a0.z + a1.z + a2.z + a3.z + a4.z + a5.z + a6.z + a7.z;
        acc.w += a0.w + a1.w + a2.w + a3.w + a4.w + a5.w + a6.w + a7.w;
    }
    for (; j < cnt; ++j) {
        float4 a = h4tof4(g2[e[j] * 8 + l]);
        acc.x += a.x; acc.y += a.y; acc.z += a.z; acc.w += a.w;
    }

    const float dv = dinv[n];
    float4 y = make_float4(0.f, 0.f, 0.f, 0.f);
    #pragma unroll
    for (int m = 0; m < 8; ++m) {
        float4 sv;
        sv.x = __shfl(acc.x, m, 8);
        sv.y = __shfl(acc.y, m, 8);
        sv.z = __shfl(acc.z, m, 8);
        sv.w = __shfl(acc.w, m, 8);
        y.x += dot4(W3s[(4 * l + 0) * 9 + m], sv);
        y.y += dot4(W3s[(4 * l + 1) * 9 + m], sv);
        y.z += dot4(W3s[(4 * l + 2) * 9 + m], sv);
        y.w += dot4(W3s[(4 * l + 3) * 9 + m], sv);
    }
    const float4 b3v = ((const float4*)b3)[l];
    float4 h;
    h.x = fmaxf(b3v.x + dv * y.x, 0.f);
    h.y = fmaxf(b3v.y + dv * y.y, 0.f);
    h.z = fmaxf(b3v.z + dv * y.z, 0.f);
    h.w = fmaxf(b3v.w + dv * y.w, 0.f);

    float4 ya = make_float4(0.f, 0.f, 0.f, 0.f);
    float4 yb = make_float4(0.f, 0.f, 0.f, 0.f);
    #pragma unroll
    for (int m = 0; m < 8; ++m) {
        float4 hv;
        hv.x = __shfl(h.x, m, 8);
        hv.y = __shfl(h.y, m, 8);
        hv.z = __shfl(h.z, m, 8);
        hv.w = __shfl(h.w, m, 8);
        ya.x += dot4(W4s[(4 * l + 0) * 9 + m], hv);
        ya.y += dot4(W4s[(4 * l + 1) * 9 + m], hv);
        ya.z += dot4(W4s[(4 * l + 2) * 9 + m], hv);
        ya.w += dot4(W4s[(4 * l + 3) * 9 + m], hv);
        yb.x += dot4(W4s[(32 + 4 * l + 0) * 9 + m], hv);
        yb.y += dot4(W4s[(32 + 4 * l + 1) * 9 + m], hv);
        yb.z += dot4(W4s[(32 + 4 * l + 2) * 9 + m], hv);
        yb.w += dot4(W4s[(32 + 4 * l + 3) * 9 + m], hv);
    }
    const float4 b4a = ((const float4*)b4)[l];
    const float4 b4b = ((const float4*)b4)[8 + l];
    ya.x += b4a.x; ya.y += b4a.y; ya.z += b4a.z; ya.w += b4a.w;
    yb.x += b4b.x; yb.y += b4b.y; yb.z += b4b.z; yb.w += b4b.w;
    out4[n * 16 + l] = ya;
    out4[n * 16 + 8 + l] = yb;
}

// ---------------- launcher ----------------

extern "C" void kernel_launch(void* const* d_in, const int* in_sizes, int n_in,
                              void* d_out, int out_size, void* d_ws, size_t ws_size,
                              hipStream_t stream) {
    const float* x   = (const float*)d_in[0];
    const int*   ei  = (const int*)d_in[1];
    const int*   row = ei;             // sources
    const int*   col = ei + N_EDGES;   // targets
    const float* W0 = (const float*)d_in[2];
    const float* b0 = (const float*)d_in[3];
    const float* W1 = (const float*)d_in[4];
    const float* b1 = (const float*)d_in[5];
    const float* W2 = (const float*)d_in[6];
    const float* b2 = (const float*)d_in[7];
    const float* W3 = (const float*)d_in[8];
    const float* b3 = (const float*)d_in[9];
    const float* W4 = (const float*)d_in[10];
    const float* b4 = (const float*)d_in[11];
    float* out = (float*)d_out;

    const int EB = (N_EDGES + 255) / 256;           // 12500
    const int NB256 = (N_NODES + 255) / 256;        // 391
    const int NB1024 = (N_NODES + 1023) / 1024;     // 98
    const int CB = (N_EDGES + BCHUNK - 1) / BCHUNK; // 391
    const int UNITS = (N_NODES + 31) / 32;          // 3125
    const int LB0 = (UNITS + 3) / 4;                // 782
    const int MB = (N_NODES + 63) / 64;             // 1563 (16 nodes/wave, 4 waves)
    const int PB2 = (N_NODES + 31) / 32;            // fallback

    // fast-path layout: bucket | dinv | degc | bins | union(pair-slabs | gA,gB)
    const size_t SLAB_BYTES = (size_t)NBIN * CAPB * 4;          // 19.2MB
    const size_t G_BYTES = 2ull * NP * 8 * 8;                   // 12.8MB (gA+gB)
    const size_t UNION_BYTES = SLAB_BYTES > G_BYTES ? SLAB_BYTES : G_BYTES;
    const size_t FAST_BYTES =
        (size_t)N_NODES * CAP * 4 + 2ull * NP * 4 + 3ull * 512 * 4 + UNION_BYTES;

    if (ws_size >= FAST_BYTES) {
        int*   bucket    = (int*)d_ws;                          // N_NODES*CAP
        float* dinv      = (float*)(bucket + (size_t)N_NODES * CAP);
        int*   degc      = (int*)(dinv + NP);
        int*   binCnt    = degc + NP;                           // 512 (unused)
        int*   binStart  = binCnt + 512;                        // 512 (unused)
        int*   binCursor = binStart + 512;                      // 512
        char*  uni       = (char*)(binCursor + 512);
        unsigned* pairs  = (unsigned*)uni;                      // build-time only
        uint2* gA        = (uint2*)uni;                         // after build
        uint2* gB        = gA + (size_t)NP * 4 * 2;             // NP*8 uint2 each

        hipMemsetAsync(binCursor, 0, 512 * sizeof(int), stream);
        k_binscatter<<<CB, 256, 0, stream>>>(row, col, binCursor, pairs);
        k_binbuild<<<NBIN, 256, 0, stream>>>(pairs, binCursor,
                                             bucket, degc, dinv);

        k_lin0_mfma<<<LB0, 256, 0, stream>>>(x, W0, b0, dinv, gA);

        k_prop_mfma<<<MB, 256, 0, stream>>>(gA, bucket, degc, dinv, W1, b1, gB);
        k_prop_mfma<<<MB, 256, 0, stream>>>(gB, bucket, degc, dinv, W2, b2, gA);
        k_last_mfma<<<MB, 256, 0, stream>>>(gA, bucket, degc, dinv,
                                            W3, b3, W4, b4, (float4*)out);
    } else {
        // ---- fallback: two-pass compact CSR ----
        int*   deg    = (int*)d_ws;                   // NP
        int*   rowptr = deg + NP;                     // NP
        int*   cursor = rowptr + NP;                  // NP
        int*   bsum   = cursor + NP;                  // 128
        float* dinv   = (float*)(bsum + 128);         // NP
        int*   csr    = (int*)(dinv + NP);            // N_EDGES
        uint2* gA     = (uint2*)(csr + N_EDGES);      // N*8
        uint2* gB     = gA + (size_t)N_NODES * 8;     // N*8

        hipMemsetAsync(deg, 0, (size_t)NP * 3 * sizeof(int), stream);
        k_hist<<<EB, 256, 0, stream>>>(col, deg);
        k_scan1<<<NB1024, 1024, 0, stream>>>(deg, rowptr, bsum);
        k_scan2<<<1, 128, 0, stream>>>(bsum, NB1024);
        k_scan3<<<NB256, 256, 0, stream>>>(rowptr, bsum);
        k_dinv<<<NB256, 256, 0, stream>>>(deg, 1, dinv, cursor);
        hipMemsetAsync(cursor, 0, (size_t)NP * sizeof(int), stream);
        k_scatter<<<EB, 256, 0, stream>>>(row, col, rowptr, cursor, csr);

        k_lin0_mfma<<<LB0, 256, 0, stream>>>(x, W0, b0, dinv, gA);

        k_prop2<<<PB2, 256, 0, stream>>>(gA, csr, rowptr, deg, 1 << 30,
                                         dinv, W1, b1, gB);
        k_prop2<<<PB2, 256, 0, stream>>>(gB, csr, rowptr, deg, 1 << 30,
                                         dinv, W2, b2, gA);
        k_last2<<<PB2, 256, 0, stream>>>(gA, csr, rowptr, deg, 1 << 30,
                                         dinv, W3, b3, W4, b4, (float4*)out);
    }
}

// Round 7
// 412.874 us; speedup vs baseline: 5.0637x; 1.0074x over previous
//
#include <hip/hip_runtime.h>
#include <hip/hip_fp16.h>

#define N_NODES 100000
#define N_EDGES 3200000
#define IN_C 256
#define HID 32
#define OUT_C 64
#define CAP 80        // padded bucket capacity (Poisson(32): P(deg>80) ~ 1e-11/node)
#define NP 100032
#define BINW 256      // nodes per bin
#define BSH 8         // bin = col >> BSH
#define NBIN 391      // ceil(N_NODES / BINW)
#define BCHUNK 4096   // edges per block in scatter (32KB LDS -> 5 blocks/CU)
#define CAPB 12288    // per-bin pair-slab capacity (Poisson(8192) + 45 sigma)

typedef _Float16 f16x8 __attribute__((ext_vector_type(8)));
typedef float f32x4 __attribute__((ext_vector_type(4)));

__device__ __forceinline__ float dot4(const float4 a, const float4 b) {
    return a.x * b.x + a.y * b.y + a.z * b.z + a.w * b.w;
}

// fp16x4 <-> fp32x4 pack helpers
__device__ __forceinline__ float4 h4tof4(uint2 v) {
    __half2 a = *reinterpret_cast<__half2*>(&v.x);
    __half2 b = *reinterpret_cast<__half2*>(&v.y);
    float2 fa = __half22float2(a), fb = __half22float2(b);
    return make_float4(fa.x, fa.y, fb.x, fb.y);
}
__device__ __forceinline__ uint2 f4toh4(float4 f) {
    __half2 a = __float22half2_rn(make_float2(f.x, f.y));
    __half2 b = __float22half2_rn(make_float2(f.z, f.w));
    uint2 v;
    v.x = *reinterpret_cast<unsigned int*>(&a);
    v.y = *reinterpret_cast<unsigned int*>(&b);
    return v;
}

// accumulate 8 halves (one uint4) into 8 f32
__device__ __forceinline__ void h8acc(uint4 v, float* acc) {
    __half2* p = reinterpret_cast<__half2*>(&v);
    #pragma unroll
    for (int i = 0; i < 4; ++i) {
        float2 f = __half22float2(p[i]);
        acc[2 * i] += f.x;
        acc[2 * i + 1] += f.y;
    }
}

__device__ __forceinline__ unsigned packh2(_Float16 a, _Float16 b) {
    unsigned short ua = __builtin_bit_cast(unsigned short, a);
    unsigned short ub = __builtin_bit_cast(unsigned short, b);
    return (unsigned)ua | ((unsigned)ub << 16);
}

// ---------------- graph build: binned, single-pass reservation ----------------

// LDS-staged scatter of packed edges into per-bin slabs (bin b owns
// pairs[b*CAPB .. b*CAPB+CAPB)).  Pack: p = (row << 8) | (col & 255).
// Per chunk: LDS hist -> LDS exclusive scan -> bin-sorted staging in LDS ->
// one global atomicAdd per non-empty bin (cursor starts at 0) ->
// linear coalesced flush into the bin's slab.
// BCHUNK=4096 keeps LDS at 32KB -> 5 blocks/CU (was 56KB -> 2 blocks/CU,
// which left the latency chain unhidden: VALUBusy 3.3%, Occ 13%).
__global__ __launch_bounds__(256) void k_binscatter(const int* __restrict__ row,
                                                    const int* __restrict__ col,
                                                    int* __restrict__ binCursor,
                                                    unsigned* __restrict__ pairs) {
    __shared__ int lcnt[512];
    __shared__ int lofs[512];
    __shared__ int gbase[512];
    __shared__ int sbuf[2][256];
    __shared__ unsigned stage[BCHUNK];
    __shared__ unsigned short sbin[BCHUNK];
    const int t = threadIdx.x;
    for (int i = t; i < 512; i += 256) lcnt[i] = 0;
    __syncthreads();

    const int e0 = blockIdx.x * BCHUNK;
    const int e1 = min(N_EDGES, e0 + BCHUNK);
    const int cn = e1 - e0;

    for (int i = e0 + t; i < e1; i += 256)
        atomicAdd(&lcnt[col[i] >> BSH], 1);
    __syncthreads();

    const int a0 = lcnt[2 * t], a1 = lcnt[2 * t + 1];
    sbuf[0][t] = a0 + a1;
    __syncthreads();
    int s = 0;
    for (int off = 1; off < 256; off <<= 1) {
        int d = s ^ 1;
        int v = sbuf[s][t];
        if (t >= off) v += sbuf[s][t - off];
        sbuf[d][t] = v;
        __syncthreads();
        s = d;
    }
    const int excl = sbuf[s][t] - (a0 + a1);
    lofs[2 * t] = excl;
    lofs[2 * t + 1] = excl + a0;
    __syncthreads();

    for (int i = t; i < 512; i += 256) {
        int c = lcnt[i];
        gbase[i] = c ? atomicAdd(&binCursor[i], c) : 0;
        lcnt[i] = 0;
    }
    __syncthreads();

    for (int i = e0 + t; i < e1; i += 256) {
        int cc = col[i];
        int b = cc >> BSH;
        int p = lofs[b] + atomicAdd(&lcnt[b], 1);
        stage[p] = ((unsigned)row[i] << 8) | (unsigned)(cc & 255);
        sbin[p] = (unsigned short)b;
    }
    __syncthreads();

    for (int i = t; i < cn; i += 256) {
        int b = sbin[i];
        int pos = gbase[b] + (i - lofs[b]);
        if (pos < CAPB)
            pairs[(size_t)b * CAPB + pos] = stage[i];
    }
}

// per-bin bucket build from the bin's slab; also emits degc + dinv.
__global__ __launch_bounds__(256) void k_binbuild(const unsigned* __restrict__ pairs,
                                                  const int* __restrict__ binCursor,
                                                  int* __restrict__ bucket,
                                                  int* __restrict__ degc,
                                                  float* __restrict__ dinv) {
    __shared__ int cur[BINW];
    const int t = threadIdx.x;
    const int bin = blockIdx.x;
    const int base = bin * BINW;
    cur[t] = 0;
    __syncthreads();
    const unsigned* __restrict__ slab = pairs + (size_t)bin * CAPB;
    const int cn = min(binCursor[bin], CAPB);
    for (int i = t; i < cn; i += 256) {
        unsigned p = slab[i];
        int c = (int)(p & 255u);
        int pos = atomicAdd(&cur[c], 1);
        if (pos < CAP) bucket[(size_t)(base + c) * CAP + pos] = (int)(p >> 8);
    }
    __syncthreads();
    int n = base + t;
    if (n < N_NODES) {
        int d = cur[t];
        degc[n] = d;
        dinv[n] = 1.0f / sqrtf((float)(d + 1)); // +1 self loop
    }
}

// ---------------- graph build: fallback path (two-pass compact CSR) ----------

__global__ void k_hist(const int* __restrict__ col, int* __restrict__ deg) {
    int i = blockIdx.x * 256 + threadIdx.x;
    if (i < N_EDGES) atomicAdd(&deg[col[i]], 1);
}

__global__ void k_scan1(const int* __restrict__ deg, int* __restrict__ rowptr,
                        int* __restrict__ bsum) {
    __shared__ int buf[2][1024];
    const int t = threadIdx.x, b = blockIdx.x;
    const int i = b * 1024 + t;
    int v = (i < N_NODES) ? deg[i] : 0;
    buf[0][t] = v;
    __syncthreads();
    int src = 0;
    for (int off = 1; off < 1024; off <<= 1) {
        int dst = src ^ 1;
        int val = buf[src][t];
        if (t >= off) val += buf[src][t - off];
        buf[dst][t] = val;
        __syncthreads();
        src = dst;
    }
    int incl = buf[src][t];
    if (i < N_NODES) rowptr[i] = incl - v;
    if (t == 1023) bsum[b] = incl;
}

__global__ void k_scan2(int* __restrict__ bsum, int nb) {
    __shared__ int buf[2][128];
    const int t = threadIdx.x;
    int v = (t < nb) ? bsum[t] : 0;
    buf[0][t] = v;
    __syncthreads();
    int src = 0;
    for (int off = 1; off < 128; off <<= 1) {
        int dst = src ^ 1;
        int val = buf[src][t];
        if (t >= off) val += buf[src][t - off];
        buf[dst][t] = val;
        __syncthreads();
        src = dst;
    }
    if (t < nb) bsum[t] = buf[src][t] - v;
}

__global__ void k_scan3(int* __restrict__ rowptr, const int* __restrict__ bsum) {
    int i = blockIdx.x * 256 + threadIdx.x;
    if (i < N_NODES) rowptr[i] += bsum[i >> 10];
}

__global__ void k_dinv(const int* __restrict__ cnt, int stride,
                       float* __restrict__ dinv, int* __restrict__ degc) {
    int i = blockIdx.x * 256 + threadIdx.x;
    if (i < N_NODES) {
        int d = cnt[i * stride];
        degc[i] = d;
        dinv[i] = 1.0f / sqrtf((float)(d + 1));
    }
}

__global__ void k_scatter(const int* __restrict__ row, const int* __restrict__ col,
                          const int* __restrict__ rowptr, int* __restrict__ cursor,
                          int* __restrict__ csr) {
    int i = blockIdx.x * 256 + threadIdx.x;
    if (i < N_EDGES) {
        int c = col[i];
        int pos = rowptr[c] + atomicAdd(&cursor[c], 1);
        csr[pos] = row[i];
    }
}

// ---------------- dense layer 0 (MFMA) ----------------
__global__ __launch_bounds__(256) void k_lin0_mfma(
        const float* __restrict__ x,
        const float* __restrict__ W0,   // [32][256]
        const float* __restrict__ b0,   // [32]
        const float* __restrict__ dinv,
        uint2* __restrict__ g2) {
    __shared__ f16x8 WH[1024];   // [mt(2)][ks(8)][lane(64)] fragment-packed
    __shared__ f16x8 WL[1024];

    const int t = threadIdx.x;
    const int w = t >> 6;        // wave 0..3
    const int l = t & 63;
    const int lr = l & 15;       // within-tile row/col index
    const int lg = l >> 4;       // k-group 0..3

    for (int s = t; s < 1024; s += 256) {
        const int lane = s & 63;
        const int mtks = s >> 6;
        const int ks = mtks & 7, mt = mtks >> 3;
        const float* wr = W0 + (size_t)(mt * 16 + (lane & 15)) * IN_C
                             + ks * 32 + (lane >> 4) * 8;
        float4 a0 = *(const float4*)(wr);
        float4 a1 = *(const float4*)(wr + 4);
        float v[8] = {a0.x, a0.y, a0.z, a0.w, a1.x, a1.y, a1.z, a1.w};
        f16x8 h, lo;
        #pragma unroll
        for (int e = 0; e < 8; ++e) {
            float sv = v[e] * 16.0f;          // prescale: Wl stays f16-normal
            _Float16 hh = (_Float16)sv;
            h[e] = hh;
            lo[e] = (_Float16)(sv - (float)hh);
        }
        WH[s] = h;
        WL[s] = lo;
    }
    __syncthreads();

    const int unit = blockIdx.x * 4 + w;       // 32 nodes per unit
    if (unit * 32 >= N_NODES) return;
    const int n0 = unit * 32;

    f32x4 acc[2][2];
    #pragma unroll
    for (int mt = 0; mt < 2; ++mt)
        #pragma unroll
        for (int nt = 0; nt < 2; ++nt)
            acc[mt][nt] = (f32x4){0.f, 0.f, 0.f, 0.f};

    const float* xr0 = x + (size_t)(n0 + lr) * IN_C + lg * 8;        // nt=0
    const float* xr1 = x + (size_t)(n0 + 16 + lr) * IN_C + lg * 8;   // nt=1

    #pragma unroll
    for (int ks = 0; ks < 8; ++ks) {
        float4 u0 = *(const float4*)(xr0 + ks * 32);
        float4 u1 = *(const float4*)(xr0 + ks * 32 + 4);
        float4 v0 = *(const float4*)(xr1 + ks * 32);
        float4 v1 = *(const float4*)(xr1 + ks * 32 + 4);
        float fu[8] = {u0.x, u0.y, u0.z, u0.w, u1.x, u1.y, u1.z, u1.w};
        float fv[8] = {v0.x, v0.y, v0.z, v0.w, v1.x, v1.y, v1.z, v1.w};
        f16x8 xh0, xl0, xh1, xl1;
        #pragma unroll
        for (int e = 0; e < 8; ++e) {
            _Float16 h0 = (_Float16)fu[e];
            xh0[e] = h0;
            xl0[e] = (_Float16)(fu[e] - (float)h0);
            _Float16 h1 = (_Float16)fv[e];
            xh1[e] = h1;
            xl1[e] = (_Float16)(fv[e] - (float)h1);
        }
        #pragma unroll
        for (int mt = 0; mt < 2; ++mt) {
            f16x8 wh = WH[mt * 512 + ks * 64 + l];
            f16x8 wl = WL[mt * 512 + ks * 64 + l];
            acc[mt][0] = __builtin_amdgcn_mfma_f32_16x16x32_f16(wh, xh0, acc[mt][0], 0, 0, 0);
            acc[mt][0] = __builtin_amdgcn_mfma_f32_16x16x32_f16(wh, xl0, acc[mt][0], 0, 0, 0);
            acc[mt][0] = __builtin_amdgcn_mfma_f32_16x16x32_f16(wl, xh0, acc[mt][0], 0, 0, 0);
            acc[mt][1] = __builtin_amdgcn_mfma_f32_16x16x32_f16(wh, xh1, acc[mt][1], 0, 0, 0);
            acc[mt][1] = __builtin_amdgcn_mfma_f32_16x16x32_f16(wh, xl1, acc[mt][1], 0, 0, 0);
            acc[mt][1] = __builtin_amdgcn_mfma_f32_16x16x32_f16(wl, xh1, acc[mt][1], 0, 0, 0);
        }
    }

    #pragma unroll
    for (int nt = 0; nt < 2; ++nt) {
        const int node = n0 + nt * 16 + lr;
        const float dv = dinv[node];
        #pragma unroll
        for (int mt = 0; mt < 2; ++mt) {
            const float4 bb = *(const float4*)(b0 + mt * 16 + lg * 4);
            f32x4 a = acc[mt][nt];
            float4 r = make_float4((a[0] * 0.0625f + bb.x) * dv,
                                   (a[1] * 0.0625f + bb.y) * dv,
                                   (a[2] * 0.0625f + bb.z) * dv,
                                   (a[3] * 0.0625f + bb.w) * dv);
            g2[(size_t)node * 8 + mt * 4 + lg] = f4toh4(r);
        }
    }
}

// ---------------- MFMA propagate+linear (fast path) ----------------
// Wave = 16 nodes, 4 lanes/node. Lane l: node = n0 + (l&15), channels
// (l>>4)*8 .. +7 (one uint4 of g2 per gather = MFMA B-fragment layout).
// Aggregate in fp32, f16-split, then y = W(32x32) @ agg via 6 split-MFMAs.
__global__ __launch_bounds__(256) void k_prop_mfma(
        const uint2* __restrict__ g2, const int* __restrict__ idx,
        const int* __restrict__ cnt_arr,
        const float* __restrict__ dinv,
        const float* __restrict__ W, const float* __restrict__ b,
        uint2* __restrict__ gout2) {
    __shared__ f16x8 WH[128], WL[128];   // A-fragments, 2 out-ch tiles
    const int t = threadIdx.x;
    if (t < 128) {
        const int lane = t & 63, mt = t >> 6;
        const float* wr = W + (size_t)(mt * 16 + (lane & 15)) * HID + (lane >> 4) * 8;
        f16x8 h, lo;
        #pragma unroll
        for (int e = 0; e < 8; ++e) {
            float sv = wr[e] * 8.0f;          // prescale x8: Wl stays f16-normal
            _Float16 hh = (_Float16)sv;
            h[e] = hh;
            lo[e] = (_Float16)(sv - (float)hh);
        }
        WH[t] = h;
        WL[t] = lo;
    }
    __syncthreads();

    const int l = t & 63;
    const int tile = blockIdx.x * 4 + (t >> 6);
    const int n0 = tile * 16;
    if (n0 >= N_NODES) return;
    const int node = n0 + (l & 15);
    const int lg = l >> 4;

    const uint4* __restrict__ g4 = (const uint4*)g2;
    float acc[8];
    #pragma unroll
    for (int i = 0; i < 8; ++i) acc[i] = 0.f;
    h8acc(g4[(size_t)node * 4 + lg], acc);     // self loop

    const int cn = min(cnt_arr[node], CAP);
    const int* __restrict__ e = idx + (size_t)node * CAP;
    int j = 0;
    for (; j + 8 <= cn; j += 8) {
        int4 ra = *(const int4*)(e + j);
        int4 rb = *(const int4*)(e + j + 4);
        uint4 v0 = g4[(size_t)ra.x * 4 + lg];
        uint4 v1 = g4[(size_t)ra.y * 4 + lg];
        uint4 v2 = g4[(size_t)ra.z * 4 + lg];
        uint4 v3 = g4[(size_t)ra.w * 4 + lg];
        uint4 v4 = g4[(size_t)rb.x * 4 + lg];
        uint4 v5 = g4[(size_t)rb.y * 4 + lg];
        uint4 v6 = g4[(size_t)rb.z * 4 + lg];
        uint4 v7 = g4[(size_t)rb.w * 4 + lg];
        h8acc(v0, acc); h8acc(v1, acc); h8acc(v2, acc); h8acc(v3, acc);
        h8acc(v4, acc); h8acc(v5, acc); h8acc(v6, acc); h8acc(v7, acc);
    }
    for (; j < cn; ++j) h8acc(g4[(size_t)e[j] * 4 + lg], acc);

    // f16 split of aggregate (B-fragment)
    f16x8 bh, bl;
    #pragma unroll
    for (int i = 0; i < 8; ++i) {
        _Float16 hh = (_Float16)acc[i];
        bh[i] = hh;
        bl[i] = (_Float16)(acc[i] - (float)hh);
    }

    f32x4 c0 = (f32x4){0.f, 0.f, 0.f, 0.f};
    f32x4 c1 = (f32x4){0.f, 0.f, 0.f, 0.f};
    {
        f16x8 wh0 = WH[l], wl0 = WL[l];
        f16x8 wh1 = WH[64 + l], wl1 = WL[64 + l];
        c0 = __builtin_amdgcn_mfma_f32_16x16x32_f16(wh0, bh, c0, 0, 0, 0);
        c0 = __builtin_amdgcn_mfma_f32_16x16x32_f16(wh0, bl, c0, 0, 0, 0);
        c0 = __builtin_amdgcn_mfma_f32_16x16x32_f16(wl0, bh, c0, 0, 0, 0);
        c1 = __builtin_amdgcn_mfma_f32_16x16x32_f16(wh1, bh, c1, 0, 0, 0);
        c1 = __builtin_amdgcn_mfma_f32_16x16x32_f16(wh1, bl, c1, 0, 0, 0);
        c1 = __builtin_amdgcn_mfma_f32_16x16x32_f16(wl1, bh, c1, 0, 0, 0);
    }

    const float dv = dinv[node];
    #pragma unroll
    for (int mt = 0; mt < 2; ++mt) {
        const f32x4 bb = *(const f32x4*)(b + mt * 16 + lg * 4);
        f32x4 a = mt ? c1 : c0;
        float4 r;
        r.x = fmaxf(bb[0] + dv * (a[0] * 0.125f), 0.f) * dv;
        r.y = fmaxf(bb[1] + dv * (a[1] * 0.125f), 0.f) * dv;
        r.z = fmaxf(bb[2] + dv * (a[2] * 0.125f), 0.f) * dv;
        r.w = fmaxf(bb[3] + dv * (a[3] * 0.125f), 0.f) * dv;
        gout2[(size_t)node * 8 + mt * 4 + lg] = f4toh4(r);
    }
}

// Last layer: agg -> (W3,relu) -> h -> (W4) -> out(64, fp32)
__global__ __launch_bounds__(256) void k_last_mfma(
        const uint2* __restrict__ g2, const int* __restrict__ idx,
        const int* __restrict__ cnt_arr,
        const float* __restrict__ dinv,
        const float* __restrict__ W3, const float* __restrict__ b3,
        const float* __restrict__ W4, const float* __restrict__ b4,
        float4* __restrict__ out4) {
    __shared__ f16x8 WH3[128], WL3[128];
    __shared__ f16x8 WH4[256], WL4[256];
    const int t = threadIdx.x;
    if (t < 128) {
        const int lane = t & 63, mt = t >> 6;
        const float* wr = W3 + (size_t)(mt * 16 + (lane & 15)) * HID + (lane >> 4) * 8;
        f16x8 h, lo;
        #pragma unroll
        for (int e = 0; e < 8; ++e) {
            float sv = wr[e] * 8.0f;
            _Float16 hh = (_Float16)sv;
            h[e] = hh;
            lo[e] = (_Float16)(sv - (float)hh);
        }
        WH3[t] = h;
        WL3[t] = lo;
    }
    {
        const int lane = t & 63, mt = t >> 6;   // mt 0..3
        const float* wr = W4 + (size_t)(mt * 16 + (lane & 15)) * HID + (lane >> 4) * 8;
        f16x8 h, lo;
        #pragma unroll
        for (int e = 0; e < 8; ++e) {
            float sv = wr[e] * 8.0f;
            _Float16 hh = (_Float16)sv;
            h[e] = hh;
            lo[e] = (_Float16)(sv - (float)hh);
        }
        WH4[t] = h;
        WL4[t] = lo;
    }
    __syncthreads();

    const int l = t & 63;
    const int tile = blockIdx.x * 4 + (t >> 6);
    const int n0 = tile * 16;
    if (n0 >= N_NODES) return;
    const int nl = l & 15;
    const int node = n0 + nl;
    const int lg = l >> 4;

    const uint4* __restrict__ g4 = (const uint4*)g2;
    float acc[8];
    #pragma unroll
    for (int i = 0; i < 8; ++i) acc[i] = 0.f;
    h8acc(g4[(size_t)node * 4 + lg], acc);     // self loop

    const int cn = min(cnt_arr[node], CAP);
    const int* __restrict__ e = idx + (size_t)node * CAP;
    int j = 0;
    for (; j + 8 <= cn; j += 8) {
        int4 ra = *(const int4*)(e + j);
        int4 rb = *(const int4*)(e + j + 4);
        uint4 v0 = g4[(size_t)ra.x * 4 + lg];
        uint4 v1 = g4[(size_t)ra.y * 4 + lg];
        uint4 v2 = g4[(size_t)ra.z * 4 + lg];
        uint4 v3 = g4[(size_t)ra.w * 4 + lg];
        uint4 v4 = g4[(size_t)rb.x * 4 + lg];
        uint4 v5 = g4[(size_t)rb.y * 4 + lg];
        uint4 v6 = g4[(size_t)rb.z * 4 + lg];
        uint4 v7 = g4[(size_t)rb.w * 4 + lg];
        h8acc(v0, acc); h8acc(v1, acc); h8acc(v2, acc); h8acc(v3, acc);
        h8acc(v4, acc); h8acc(v5, acc); h8acc(v6, acc); h8acc(v7, acc);
    }
    for (; j < cn; ++j) h8acc(g4[(size_t)e[j] * 4 + lg], acc);

    f16x8 bh, bl;
    #pragma unroll
    for (int i = 0; i < 8; ++i) {
        _Float16 hh = (_Float16)acc[i];
        bh[i] = hh;
        bl[i] = (_Float16)(acc[i] - (float)hh);
    }

    // stage 1: y = W3 @ agg, h = relu(b3 + dv*y)
    f32x4 c0 = (f32x4){0.f, 0.f, 0.f, 0.f};
    f32x4 c1 = (f32x4){0.f, 0.f, 0.f, 0.f};
    {
        f16x8 wh0 = WH3[l], wl0 = WL3[l];
        f16x8 wh1 = WH3[64 + l], wl1 = WL3[64 + l];
        c0 = __builtin_amdgcn_mfma_f32_16x16x32_f16(wh0, bh, c0, 0, 0, 0);
        c0 = __builtin_amdgcn_mfma_f32_16x16x32_f16(wh0, bl, c0, 0, 0, 0);
        c0 = __builtin_amdgcn_mfma_f32_16x16x32_f16(wl0, bh, c0, 0, 0, 0);
        c1 = __builtin_amdgcn_mfma_f32_16x16x32_f16(wh1, bh, c1, 0, 0, 0);
        c1 = __builtin_amdgcn_mfma_f32_16x16x32_f16(wh1, bl, c1, 0, 0, 0);
        c1 = __builtin_amdgcn_mfma_f32_16x16x32_f16(wl1, bh, c1, 0, 0, 0);
    }

    const float dv = dinv[node];
    const f32x4 b3a = *(const f32x4*)(b3 + lg * 4);
    const f32x4 b3b = *(const f32x4*)(b3 + 16 + lg * 4);
    float h0[4], h1[4];
    #pragma unroll
    for (int r = 0; r < 4; ++r) {
        h0[r] = fmaxf(b3a[r] + dv * (c0[r] * 0.125f), 0.f);
        h1[r] = fmaxf(b3b[r] + dv * (c1[r] * 0.125f), 0.f);
    }

    // f16-split h, packed as half2 words: ph[mt][p] = ch (mt*16+lg*4+2p, +1)
    unsigned ph[2][2], pl_[2][2];
    #pragma unroll
    for (int p = 0; p < 2; ++p) {
        _Float16 a0 = (_Float16)h0[2 * p], a1 = (_Float16)h0[2 * p + 1];
        _Float16 l0 = (_Float16)(h0[2 * p] - (float)a0);
        _Float16 l1 = (_Float16)(h0[2 * p + 1] - (float)a1);
        ph[0][p] = packh2(a0, a1);
        pl_[0][p] = packh2(l0, l1);
        _Float16 c0_ = (_Float16)h1[2 * p], c1_ = (_Float16)h1[2 * p + 1];
        _Float16 d0 = (_Float16)(h1[2 * p] - (float)c0_);
        _Float16 d1 = (_Float16)(h1[2 * p + 1] - (float)c1_);
        ph[1][p] = packh2(c0_, c1_);
        pl_[1][p] = packh2(d0, d1);
    }

    // redistribute: dest lane (nl,lg) needs h-ch lg*8..+7 of node nl.
    union { unsigned u[4]; f16x8 v; } Bh, Bl;
    #pragma unroll
    for (int q = 0; q < 4; ++q) {
        int src = nl + 16 * ((lg & 1) * 2 + (q >> 1));
        unsigned a0 = (unsigned)__shfl((int)ph[0][q & 1], src, 64);
        unsigned a1 = (unsigned)__shfl((int)ph[1][q & 1], src, 64);
        Bh.u[q] = (lg >= 2) ? a1 : a0;
        unsigned c0_ = (unsigned)__shfl((int)pl_[0][q & 1], src, 64);
        unsigned c1_ = (unsigned)__shfl((int)pl_[1][q & 1], src, 64);
        Bl.u[q] = (lg >= 2) ? c1_ : c0_;
    }

    // stage 2: out = W4 @ h + b4 (4 out-ch tiles)
    f32x4 o0 = (f32x4){0.f, 0.f, 0.f, 0.f};
    f32x4 o1 = (f32x4){0.f, 0.f, 0.f, 0.f};
    f32x4 o2 = (f32x4){0.f, 0.f, 0.f, 0.f};
    f32x4 o3 = (f32x4){0.f, 0.f, 0.f, 0.f};
    {
        f16x8 wh, wl;
        wh = WH4[l];        wl = WL4[l];
        o0 = __builtin_amdgcn_mfma_f32_16x16x32_f16(wh, Bh.v, o0, 0, 0, 0);
        o0 = __builtin_amdgcn_mfma_f32_16x16x32_f16(wh, Bl.v, o0, 0, 0, 0);
        o0 = __builtin_amdgcn_mfma_f32_16x16x32_f16(wl, Bh.v, o0, 0, 0, 0);
        wh = WH4[64 + l];   wl = WL4[64 + l];
        o1 = __builtin_amdgcn_mfma_f32_16x16x32_f16(wh, Bh.v, o1, 0, 0, 0);
        o1 = __builtin_amdgcn_mfma_f32_16x16x32_f16(wh, Bl.v, o1, 0, 0, 0);
        o1 = __builtin_amdgcn_mfma_f32_16x16x32_f16(wl, Bh.v, o1, 0, 0, 0);
        wh = WH4[128 + l];  wl = WL4[128 + l];
        o2 = __builtin_amdgcn_mfma_f32_16x16x32_f16(wh, Bh.v, o2, 0, 0, 0);
        o2 = __builtin_amdgcn_mfma_f32_16x16x32_f16(wh, Bl.v, o2, 0, 0, 0);
        o2 = __builtin_amdgcn_mfma_f32_16x16x32_f16(wl, Bh.v, o2, 0, 0, 0);
        wh = WH4[192 + l];  wl = WL4[192 + l];
        o3 = __builtin_amdgcn_mfma_f32_16x16x32_f16(wh, Bh.v, o3, 0, 0, 0);
        o3 = __builtin_amdgcn_mfma_f32_16x16x32_f16(wh, Bl.v, o3, 0, 0, 0);
        o3 = __builtin_amdgcn_mfma_f32_16x16x32_f16(wl, Bh.v, o3, 0, 0, 0);
    }

    #pragma unroll
    for (int mt = 0; mt < 4; ++mt) {
        const f32x4 bb = *(const f32x4*)(b4 + mt * 16 + lg * 4);
        f32x4 a = (mt == 0) ? o0 : (mt == 1) ? o1 : (mt == 2) ? o2 : o3;
        out4[(size_t)node * 16 + mt * 4 + lg] =
            make_float4(a[0] * 0.125f + bb[0], a[1] * 0.125f + bb[1],
                        a[2] * 0.125f + bb[2], a[3] * 0.125f + bb[3]);
    }
}

// ---------------- legacy fused propagate + linear (fallback path) ----------

__global__ __launch_bounds__(256) void k_prop2(
        const uint2* __restrict__ g2, const int* __restrict__ idx,
        const int* __restrict__ base_arr,
        const int* __restrict__ cnt_arr, int maxcnt,
        const float* __restrict__ dinv,
        const float* __restrict__ W, const float* __restrict__ b,
        uint2* __restrict__ gout2) {
    __shared__ float4 Ws[HID * 9];
    const int t = threadIdx.x;
    { int c = t >> 3, k4 = t & 7; Ws[c * 9 + k4] = ((const float4*)W)[t]; }
    __syncthreads();

    const int l = t & 7;
    const int n = blockIdx.x * 32 + (t >> 3);
    if (n >= N_NODES) return;

    int cnt = cnt_arr[n];
    if (cnt > maxcnt) cnt = maxcnt;
    const int base = base_arr[n];
    const int* __restrict__ e = idx + base;

    float4 acc = h4tof4(g2[n * 8 + l]);
    int j = 0;
    for (; j + 8 <= cnt; j += 8) {
        int r0 = e[j], r1 = e[j + 1], r2 = e[j + 2], r3 = e[j + 3];
        int r4 = e[j + 4], r5 = e[j + 5], r6 = e[j + 6], r7 = e[j + 7];
        uint2 v0 = g2[r0 * 8 + l], v1 = g2[r1 * 8 + l];
        uint2 v2 = g2[r2 * 8 + l], v3 = g2[r3 * 8 + l];
        uint2 v4 = g2[r4 * 8 + l], v5 = g2[r5 * 8 + l];
        uint2 v6 = g2[r6 * 8 + l], v7 = g2[r7 * 8 + l];
        float4 a0 = h4tof4(v0), a1 = h4tof4(v1), a2 = h4tof4(v2), a3 = h4tof4(v3);
        float4 a4 = h4tof4(v4), a5 = h4tof4(v5), a6 = h4tof4(v6), a7 = h4tof4(v7);
        acc.x += a0.x + a1.x + a2.x + a3.x + a4.x + a5.x + a6.x + a7.x;
        acc.y += a0.y + a1.y + a2.y + a3.y + a4.y + a5.y + a6.y + a7.y;
        acc.z += a0.z + a1.z + a2.z + a3.z + a4.z + a5.z + a6.z + a7.z;
        acc.w += a0.w + a1.w + a2.w + a3.w + a4.w + a5.w + a6.w + a7.w;
    }
    for (; j < cnt; ++j) {
        float4 a = h4tof4(g2[e[j] * 8 + l]);
        acc.x += a.x; acc.y += a.y; acc.z += a.z; acc.w += a.w;
    }

    const float dv = dinv[n];
    float4 y = make_float4(0.f, 0.f, 0.f, 0.f);
    #pragma unroll
    for (int m = 0; m < 8; ++m) {
        float4 sv;
        sv.x = __shfl(acc.x, m, 8);
        sv.y = __shfl(acc.y, m, 8);
        sv.z = __shfl(acc.z, m, 8);
        sv.w = __shfl(acc.w, m, 8);
        y.x += dot4(Ws[(4 * l + 0) * 9 + m], sv);
        y.y += dot4(Ws[(4 * l + 1) * 9 + m], sv);
        y.z += dot4(Ws[(4 * l + 2) * 9 + m], sv);
        y.w += dot4(Ws[(4 * l + 3) * 9 + m], sv);
    }
    const float4 bb = ((const float4*)b)[l];
    y.x = fmaxf(bb.x + dv * y.x, 0.f) * dv;
    y.y = fmaxf(bb.y + dv * y.y, 0.f) * dv;
    y.z = fmaxf(bb.z + dv * y.z, 0.f) * dv;
    y.w = fmaxf(bb.w + dv * y.w, 0.f) * dv;
    gout2[n * 8 + l] = f4toh4(y);
}

__global__ __launch_bounds__(256) void k_last2(
        const uint2* __restrict__ g2, const int* __restrict__ idx,
        const int* __restrict__ base_arr,
        const int* __restrict__ cnt_arr, int maxcnt,
        const float* __restrict__ dinv,
        const float* __restrict__ W3, const float* __restrict__ b3,
        const float* __restrict__ W4, const float* __restrict__ b4,
        float4* __restrict__ out4) {
    __shared__ float4 W3s[HID * 9];
    __shared__ float4 W4s[OUT_C * 9];
    const int t = threadIdx.x;
    { int c = t >> 3, k4 = t & 7; W3s[c * 9 + k4] = ((const float4*)W3)[t]; }
    #pragma unroll
    for (int f = t; f < 512; f += 256) {
        int c = f >> 3, k4 = f & 7;
        W4s[c * 9 + k4] = ((const float4*)W4)[f];
    }
    __syncthreads();

    const int l = t & 7;
    const int n = blockIdx.x * 32 + (t >> 3);
    if (n >= N_NODES) return;

    int cnt = cnt_arr[n];
    if (cnt > maxcnt) cnt = maxcnt;
    const int base = base_arr[n];
    const int* __restrict__ e = idx + base;

    float4 acc = h4tof4(g2[n * 8 + l]);
    int j = 0;
    for (; j + 8 <= cnt; j += 8) {
        int r0 = e[j], r1 = e[j + 1], r2 = e[j + 2], r3 = e[j + 3];
        int r4 = e[j + 4], r5 = e[j + 5], r6 = e[j + 6], r7 = e[j + 7];
        uint2 v0 = g2[r0 * 8 + l], v1 = g2[r1 * 8 + l];
        uint2 v2 = g2[r2 * 8 + l], v3 = g2[r3 * 8 + l];
        uint2 v4 = g2[r4 * 8 + l], v5 = g2[r5 * 8 + l];
        uint2 v6 = g2[r6 * 8 + l], v7 = g2[r7 * 8 + l];
        float4 a0 = h4tof4(v0), a1 = h4tof4(v1), a2 = h4tof4(v2), a3 = h4tof4(v3);
        float4 a4 = h4tof4(v4), a5 = h4tof4(v5), a6 = h4tof4(v6), a7 = h4tof4(v7);
        acc.x += a0.x + a1.x + a2.x + a3.x + a4.x + a5.x + a6.x + a7.x;
        acc.y += a0.y + a1.y + a2.y + a3.y + a4.y + a5.y + a6.y + a7.y;
        acc.z += a0.z + a1.z + a2.z + a3.z + a4.z + a5.z + a6.z + a7.z;
        acc.w += a0.w + a1.w + a2.w + a3.w + a4.w + a5.w + a6.w + a7.w;
    }
    for (; j < cnt; ++j) {
        float4 a = h4tof4(g2[e[j] * 8 + l]);
        acc.x += a.x; acc.y += a.y; acc.z += a.z; acc.w += a.w;
    }

    const float dv = dinv[n];
    float4 y = make_float4(0.f, 0.f, 0.f, 0.f);
    #pragma unroll
    for (int m = 0; m < 8; ++m) {
        float4 sv;
        sv.x = __shfl(acc.x, m, 8);
        sv.y = __shfl(acc.y, m, 8);
        sv.z = __shfl(acc.z, m, 8);
        sv.w = __shfl(acc.w, m, 8);
        y.x += dot4(W3s[(4 * l + 0) * 9 + m], sv);
        y.y += dot4(W3s[(4 * l + 1) * 9 + m], sv);
        y.z += dot4(W3s[(4 * l + 2) * 9 + m], sv);
        y.w += dot4(W3s[(4 * l + 3) * 9 + m], sv);
    }
    const float4 b3v = ((const float4*)b3)[l];
    float4 h;
    h.x = fmaxf(b3v.x + dv * y.x, 0.f);
    h.y = fmaxf(b3v.y + dv * y.y, 0.f);
    h.z = fmaxf(b3v.z + dv * y.z, 0.f);
    h.w = fmaxf(b3v.w + dv * y.w, 0.f);

    float4 ya = make_float4(0.f, 0.f, 0.f, 0.f);
    float4 yb = make_float4(0.f, 0.f, 0.f, 0.f);
    #pragma unroll
    for (int m = 0; m < 8; ++m) {
        float4 hv;
        hv.x = __shfl(h.x, m, 8);
        hv.y = __shfl(h.y, m, 8);
        hv.z = __shfl(h.z, m, 8);
        hv.w = __shfl(h.w, m, 8);
        ya.x += dot4(W4s[(4 * l + 0) * 9 + m], hv);
        ya.y += dot4(W4s[(4 * l + 1) * 9 + m], hv);
        ya.z += dot4(W4s[(4 * l + 2) * 9 + m], hv);
        ya.w += dot4(W4s[(4 * l + 3) * 9 + m], hv);
        yb.x += dot4(W4s[(32 + 4 * l + 0) * 9 + m], hv);
        yb.y += dot4(W4s[(32 + 4 * l + 1) * 9 + m], hv);
        yb.z += dot4(W4s[(32 + 4 * l + 2) * 9 + m], hv);
        yb.w += dot4(W4s[(32 + 4 * l + 3) * 9 + m], hv);
    }
    const float4 b4a = ((const float4*)b4)[l];
    const float4 b4b = ((const float4*)b4)[8 + l];
    ya.x += b4a.x; ya.y += b4a.y; ya.z += b4a.z; ya.w += b4a.w;
    yb.x += b4b.x; yb.y += b4b.y; yb.z += b4b.z; yb.w += b4b.w;
    out4[n * 16 + l] = ya;
    out4[n * 16 + 8 + l] = yb;
}

// ---------------- launcher ----------------

extern "C" void kernel_launch(void* const* d_in, const int* in_sizes, int n_in,
                              void* d_out, int out_size, void* d_ws, size_t ws_size,
                              hipStream_t stream) {
    const float* x   = (const float*)d_in[0];
    const int*   ei  = (const int*)d_in[1];
    const int*   row = ei;             // sources
    const int*   col = ei + N_EDGES;   // targets
    const float* W0 = (const float*)d_in[2];
    const float* b0 = (const float*)d_in[3];
    const float* W1 = (const float*)d_in[4];
    const float* b1 = (const float*)d_in[5];
    const float* W2 = (const float*)d_in[6];
    const float* b2 = (const float*)d_in[7];
    const float* W3 = (const float*)d_in[8];
    const float* b3 = (const float*)d_in[9];
    const float* W4 = (const float*)d_in[10];
    const float* b4 = (const float*)d_in[11];
    float* out = (float*)d_out;

    const int EB = (N_EDGES + 255) / 256;           // 12500
    const int NB256 = (N_NODES + 255) / 256;        // 391
    const int NB1024 = (N_NODES + 1023) / 1024;     // 98
    const int CB = (N_EDGES + BCHUNK - 1) / BCHUNK; // 782
    const int UNITS = (N_NODES + 31) / 32;          // 3125
    const int LB0 = (UNITS + 3) / 4;                // 782
    const int MB = (N_NODES + 63) / 64;             // 1563 (16 nodes/wave, 4 waves)
    const int PB2 = (N_NODES + 31) / 32;            // fallback

    // fast-path layout: bucket | dinv | degc | bins | union(pair-slabs | gA,gB)
    const size_t SLAB_BYTES = (size_t)NBIN * CAPB * 4;          // 19.2MB
    const size_t G_BYTES = 2ull * NP * 8 * 8;                   // 12.8MB (gA+gB)
    const size_t UNION_BYTES = SLAB_BYTES > G_BYTES ? SLAB_BYTES : G_BYTES;
    const size_t FAST_BYTES =
        (size_t)N_NODES * CAP * 4 + 2ull * NP * 4 + 3ull * 512 * 4 + UNION_BYTES;

    if (ws_size >= FAST_BYTES) {
        int*   bucket    = (int*)d_ws;                          // N_NODES*CAP
        float* dinv      = (float*)(bucket + (size_t)N_NODES * CAP);
        int*   degc      = (int*)(dinv + NP);
        int*   binCnt    = degc + NP;                           // 512 (unused)
        int*   binStart  = binCnt + 512;                        // 512 (unused)
        int*   binCursor = binStart + 512;                      // 512
        char*  uni       = (char*)(binCursor + 512);
        unsigned* pairs  = (unsigned*)uni;                      // build-time only
        uint2* gA        = (uint2*)uni;                         // after build
        uint2* gB        = gA + (size_t)NP * 4 * 2;             // NP*8 uint2 each

        hipMemsetAsync(binCursor, 0, 512 * sizeof(int), stream);
        k_binscatter<<<CB, 256, 0, stream>>>(row, col, binCursor, pairs);
        k_binbuild<<<NBIN, 256, 0, stream>>>(pairs, binCursor,
                                             bucket, degc, dinv);

        k_lin0_mfma<<<LB0, 256, 0, stream>>>(x, W0, b0, dinv, gA);

        k_prop_mfma<<<MB, 256, 0, stream>>>(gA, bucket, degc, dinv, W1, b1, gB);
        k_prop_mfma<<<MB, 256, 0, stream>>>(gB, bucket, degc, dinv, W2, b2, gA);
        k_last_mfma<<<MB, 256, 0, stream>>>(gA, bucket, degc, dinv,
                                            W3, b3, W4, b4, (float4*)out);
    } else {
        // ---- fallback: two-pass compact CSR ----
        int*   deg    = (int*)d_ws;                   // NP
        int*   rowptr = deg + NP;                     // NP
        int*   cursor = rowptr + NP;                  // NP
        int*   bsum   = cursor + NP;                  // 128
        float* dinv   = (float*)(bsum + 128);         // NP
        int*   csr    = (int*)(dinv + NP);            // N_EDGES
        uint2* gA     = (uint2*)(csr + N_EDGES);      // N*8
        uint2* gB     = gA + (size_t)N_NODES * 8;     // N*8

        hipMemsetAsync(deg, 0, (size_t)NP * 3 * sizeof(int), stream);
        k_hist<<<EB, 256, 0, stream>>>(col, deg);
        k_scan1<<<NB1024, 1024, 0, stream>>>(deg, rowptr, bsum);
        k_scan2<<<1, 128, 0, stream>>>(bsum, NB1024);
        k_scan3<<<NB256, 256, 0, stream>>>(rowptr, bsum);
        k_dinv<<<NB256, 256, 0, stream>>>(deg, 1, dinv, cursor);
        hipMemsetAsync(cursor, 0, (size_t)NP * sizeof(int), stream);
        k_scatter<<<EB, 256, 0, stream>>>(row, col, rowptr, cursor, csr);

        k_lin0_mfma<<<LB0, 256, 0, stream>>>(x, W0, b0, dinv, gA);

        k_prop2<<<PB2, 256, 0, stream>>>(gA, csr, rowptr, deg, 1 << 30,
                                         dinv, W1, b1, gB);
        k_prop2<<<PB2, 256, 0, stream>>>(gB, csr, rowptr, deg, 1 << 30,
                                         dinv, W2, b2, gA);
        k_last2<<<PB2, 256, 0, stream>>>(gA, csr, rowptr, deg, 1 << 30,
                                         dinv, W3, b3, W4, b4, (float4*)out);
    }
}